// Round 11
// baseline (818.807 us; speedup 1.0000x reference)
//
#include <hip/hip_runtime.h>
#include <hip/hip_fp16.h>

#define H_  1024
#define W_  1024
#define HW_ (H_*W_)
#define M_  524288

#define SWZ(a) ((a) + ((a)>>4))

// ---------------------------------------------------------------- complex mul
__device__ __forceinline__ float2 cmulf(float2 a, float2 b){
  return make_float2(fmaf(a.x,b.x,-(a.y*b.y)), fmaf(a.x,b.y,a.y*b.x));
}

// ---------------------------------------------------------------- radix-4 bfly
template<int DIR>
__device__ __forceinline__ void bfly4(float2 v[4], int j, int Ns){
  if (Ns>1){
    float ang = ((DIR>0)?6.28318530717958647692f:-6.28318530717958647692f)
                * (float)(j&(Ns-1)) / (float)(4*Ns);
    float s,c; __sincosf(ang,&s,&c);
    float2 w1=make_float2(c,s);
    float2 w2=cmulf(w1,w1);
    float2 w3=cmulf(w2,w1);
    v[1]=cmulf(v[1],w1); v[2]=cmulf(v[2],w2); v[3]=cmulf(v[3],w3);
  }
  float2 t0=make_float2(v[0].x+v[2].x, v[0].y+v[2].y);
  float2 t2=make_float2(v[0].x-v[2].x, v[0].y-v[2].y);
  float2 t1=make_float2(v[1].x+v[3].x, v[1].y+v[3].y);
  float2 t3=make_float2(v[1].x-v[3].x, v[1].y-v[3].y);
  float2 t3r=(DIR<0)?make_float2(t3.y,-t3.x):make_float2(-t3.y,t3.x);
  v[0]=make_float2(t0.x+t1.x,  t0.y+t1.y);
  v[1]=make_float2(t2.x+t3r.x, t2.y+t3r.y);
  v[2]=make_float2(t0.x-t1.x,  t0.y-t1.y);
  v[3]=make_float2(t2.x-t3r.x, t2.y-t3r.y);
}

template<int DIR, int NS>
__device__ __forceinline__ void fft_stage(int j, const float2* src, float2* dst){
  float2 v[4];
#pragma unroll
  for(int r=0;r<4;r++) v[r]=src[SWZ(j+256*r)];
  bfly4<DIR>(v,j,NS);
  int base = ((j & ~(NS-1))<<2) | (j&(NS-1));
#pragma unroll
  for(int r=0;r<4;r++) dst[SWZ(base+NS*r)]=v[r];
}

template<int DIR>
__device__ __forceinline__ void fft1024_core(float2 v[4], int j, float2* A, float2* B, float scale){
  bfly4<DIR>(v,j,1);
#pragma unroll
  for(int r=0;r<4;r++) A[SWZ(4*j+r)]=v[r];
  __syncthreads();
  fft_stage<DIR,4 >(j,A,B); __syncthreads();
  fft_stage<DIR,16>(j,B,A); __syncthreads();
  fft_stage<DIR,64>(j,A,B); __syncthreads();
#pragma unroll
  for(int r=0;r<4;r++) v[r]=B[SWZ(j+256*r)];
  bfly4<DIR>(v,j,256);
#pragma unroll
  for(int r=0;r<4;r++){ v[r].x*=scale; v[r].y*=scale; }
}

template<int DIR>
__global__ __launch_bounds__(256) void k_fft_rows(const float2* src, float2* dst, float scale){
  __shared__ float2 A[1088], B[1088];
  int j = threadIdx.x;
  const float2* s = src + (size_t)blockIdx.x*W_;
  float2 v[4];
#pragma unroll
  for(int r=0;r<4;r++) v[r]=s[j+256*r];
  fft1024_core<DIR>(v,j,A,B,scale);
  float2* d = dst + (size_t)blockIdx.x*W_;
#pragma unroll
  for(int r=0;r<4;r++) d[j+256*r]=v[r];
}

// 1 column per block, registers-direct; XCD-aware column swizzle so the 8
// columns sharing each 64B line live on one XCD's L2.
template<int DIR>
__global__ __launch_bounds__(256) void k_fft_cols1(float2* data, float scale){
  __shared__ float2 A[1088], B[1088];
  int tid=threadIdx.x;
  int col = ((blockIdx.x&7)<<7) + (blockIdx.x>>3);
  float2 v[4];
#pragma unroll
  for(int r=0;r<4;r++) v[r]=data[(size_t)(tid+256*r)*W_ + col];
  fft1024_core<DIR>(v,tid,A,B,scale);
#pragma unroll
  for(int r=0;r<4;r++) data[(size_t)(tid+256*r)*W_ + col]=v[r];
}

// ---------------------------------------------------------------- init: pack x, zero the 28MB fp32 accumulators (5 planes + Gy)
// and t; block 4096 builds the composed-conv tables.
// ec layout (floats): [0..99] E[oc*50+ic*25+dy*5+dx]; [100..101] C0;
// [102..119] Bb[oc*9+u]; [120..443] Btab[oc*162+u*18+ic*9+v]; [444..445] b2
__global__ __launch_bounds__(256) void k_pack(const float* xr, const float* xi, float2* X, float* t,
                                              float* Zacc,
                                              const float* w1, const float* b1,
                                              const float* w2, const float* b2, float* ec){
  __shared__ float sw1[576], sw2[576], sb1[32], sB[324];
  int tid=threadIdx.x;
  if (blockIdx.x==4096){
    for(int p=tid;p<576;p+=256){ sw1[p]=w1[p]; sw2[p]=w2[p]; }
    if(tid<32) sb1[tid]=b1[tid];
    __syncthreads();
    for(int e=tid;e<324;e+=256){
      int oc=e/162, r=e-oc*162, u=r/18, r2=r-u*18, ic=r2/9, v=r2-ic*9;
      float s=0.f;
      for(int cm=0;cm<32;cm++) s=fmaf(sw2[oc*288+cm*9+u], sw1[cm*18+ic*9+v], s);
      sB[e]=s; ec[120+e]=s;
    }
    if(tid<18){
      int oc=tid/9, u=tid-oc*9;
      float s=0.f;
      for(int cm=0;cm<32;cm++) s=fmaf(sw2[oc*288+cm*9+u], sb1[cm], s);
      ec[102+tid]=s;
    }
    if(tid<2){
      float s=b2[tid];
      for(int u=0;u<9;u++){
        float bb=0.f;
        for(int cm=0;cm<32;cm++) bb=fmaf(sw2[tid*288+cm*9+u], sb1[cm], bb);
        s+=bb;
      }
      ec[100+tid]=s;
      ec[444+tid]=b2[tid];
    }
    __syncthreads();
    if(tid<100){
      int oc=tid/50, r=tid-oc*50, ic=r/25, r2=r-ic*25, dy=r2/5, dx=r2-dy*5;
      float s=0.f;
      for(int uy=0;uy<3;uy++){ int vy=dy-uy; if(vy<0||vy>2) continue;
        for(int ux=0;ux<3;ux++){ int vx=dx-ux; if(vx<0||vx>2) continue;
          s+=sB[oc*162+(uy*3+ux)*18+ic*9+vy*3+vx];
        }
      }
      ec[tid]=s;
    }
    return;
  }
  int i = blockIdx.x*256+tid;
  X[i]=make_float2(xr[i],xi[i]);
#pragma unroll
  for(int k=0;k<7;k++) Zacc[i + (size_t)k*HW_]=0.f;    // 5 W planes + Gy (2 floats/cell)
  if (blockIdx.x==0 && tid<32) t[tid]=0.f;
}

// ---------------------------------------------------------------- direct per-point plane build (atomic scatter-add)
// Each point p with corners A=(ix,iy) B=(ix+1,iy) C=(ix,iy+1) D=(ix+1,iy+1),
// weights wA=(1-tx)(1-ty), wB=tx(1-ty), wC=(1-tx)ty, wD=tx*ty, contributes:
//   W00: wA^2@A wB^2@B wC^2@C wD^2@D ; WE[c]=T[c][c+(0,1)]: wA*wC@A, wB*wD@B
//   WS[c]=T[c][c+(1,0)]: wA*wB@A, wC*wD@C ; WSE: wA*wD@A ; WSW[c]=T[c][c+(1,-1)]: wC*wB@C
//   Gy' = Grid(y*sqrt(r)) (global 1/sqrt(rmax+1e-8) applied in k_convert).
// rmax via per-wave atomicMax on float-as-uint (valid: r>=0, t[15] zeroed).
__global__ __launch_bounds__(256) void k_build(const float* __restrict__ kt,
                                               const float* __restrict__ kre,
                                               const float* __restrict__ kim,
                                               float* __restrict__ Wacc,
                                               float2* __restrict__ GyAcc,
                                               float* t){
  int m = blockIdx.x*256+threadIdx.x;
  float kx=kt[2*m], ky=kt[2*m+1];
  float gx=kx*1024.f, gy=ky*1024.f;
  float fx=floorf(gx), fy=floorf(gy);
  float tx=gx-fx, ty=gy-fy;
  int ix=((int)fx)&1023, iy=((int)fy)&1023;
  int ix1=(ix+1)&1023, iy1=(iy+1)&1023;
  float ux=1.f-tx, uy=1.f-ty;
  float wA=ux*uy, wB=tx*uy, wC=ux*ty, wD=tx*ty;
  int cA=(ix<<10)|iy, cB=(ix1<<10)|iy, cC=(ix<<10)|iy1, cD=(ix1<<10)|iy1;
  float* WE =Wacc+(size_t)HW_;
  float* WS =Wacc+(size_t)2*HW_;
  float* WSE=Wacc+(size_t)3*HW_;
  float* WSW=Wacc+(size_t)4*HW_;
  atomicAdd(&Wacc[cA], wA*wA);
  atomicAdd(&Wacc[cB], wB*wB);
  atomicAdd(&Wacc[cC], wC*wC);
  atomicAdd(&Wacc[cD], wD*wD);
  atomicAdd(&WE [cA], wA*wC);
  atomicAdd(&WE [cB], wB*wD);
  atomicAdd(&WS [cA], wA*wB);
  atomicAdd(&WS [cC], wC*wD);
  atomicAdd(&WSE[cA], wA*wD);
  atomicAdd(&WSW[cC], wC*wB);
  float dx=kx-0.5f, dy=ky-0.5f;
  float r=sqrtf(dx*dx+dy*dy);
  float d=sqrtf(r);
  float yr=kre[m]*d, yi=kim[m]*d;
  atomicAdd(&GyAcc[cA].x, wA*yr); atomicAdd(&GyAcc[cA].y, wA*yi);
  atomicAdd(&GyAcc[cB].x, wB*yr); atomicAdd(&GyAcc[cB].y, wB*yi);
  atomicAdd(&GyAcc[cC].x, wC*yr); atomicAdd(&GyAcc[cC].y, wC*yi);
  atomicAdd(&GyAcc[cD].x, wD*yr); atomicAdd(&GyAcc[cD].y, wD*yi);
  for(int o=32;o>0;o>>=1) r=fmaxf(r,__shfl_down(r,o,64));
  if((threadIdx.x&63)==0) atomicMax((unsigned int*)&t[15], __float_as_uint(r));
}

// ---------------------------------------------------------------- fp32 accum -> fp16 planes; scale Gy by 1/sqrt(rmax+1e-8)
__global__ __launch_bounds__(256) void k_convert(const float* __restrict__ Wacc,
                                                 const float2* __restrict__ GyAcc,
                                                 __half* __restrict__ WpH,
                                                 __half2* __restrict__ GyH,
                                                 const float* __restrict__ t){
  int i = blockIdx.x*256+threadIdx.x;
  float s = 1.f/sqrtf(t[15]+1e-8f);
#pragma unroll
  for(int d=0;d<5;d++)
    WpH[(size_t)d*HW_+i]=__float2half(Wacc[(size_t)d*HW_+i]);
  float2 g=GyAcc[i];
  GyH[i]=__floats2half2_rn(g.x*s, g.y*s);
}

// ---------------------------------------------------------------- 9-tap symmetric stencil, complex field (fp16 weights)
__device__ __forceinline__ float2 t_tap(const float2* __restrict__ Fm, const float2* __restrict__ F0,
                                        const float2* __restrict__ Fp, const __half* __restrict__ WpH,
                                        int rowW, int rowWm, int c){
  int cm=(c+1023)&1023, cp=(c+1)&1023;
  const __half* W00=WpH;
  const __half* WE =WpH+(size_t)HW_;
  const __half* WS =WpH+(size_t)2*HW_;
  const __half* WSE=WpH+(size_t)3*HW_;
  const __half* WSW=WpH+(size_t)4*HW_;
  float2 f=F0[c];
  float w=__half2float(W00[rowW+c]);
  float ux=w*f.x, uy=w*f.y;
  f=F0[cp]; w=__half2float(WE [rowW +c ]); ux=fmaf(w,f.x,ux); uy=fmaf(w,f.y,uy);  // +E
  f=F0[cm]; w=__half2float(WE [rowW +cm]); ux=fmaf(w,f.x,ux); uy=fmaf(w,f.y,uy);  // -E
  f=Fp[c ]; w=__half2float(WS [rowW +c ]); ux=fmaf(w,f.x,ux); uy=fmaf(w,f.y,uy);  // +S
  f=Fm[c ]; w=__half2float(WS [rowWm+c ]); ux=fmaf(w,f.x,ux); uy=fmaf(w,f.y,uy);  // -S
  f=Fp[cp]; w=__half2float(WSE[rowW +c ]); ux=fmaf(w,f.x,ux); uy=fmaf(w,f.y,uy);  // +SE
  f=Fm[cm]; w=__half2float(WSE[rowWm+cm]); ux=fmaf(w,f.x,ux); uy=fmaf(w,f.y,uy);  // -SE
  f=Fp[cm]; w=__half2float(WSW[rowW +c ]); ux=fmaf(w,f.x,ux); uy=fmaf(w,f.y,uy);  // +SW
  f=Fm[cp]; w=__half2float(WSW[rowWm+cp]); ux=fmaf(w,f.x,ux); uy=fmaf(w,f.y,uy);  // -SW
  return make_float2(ux,uy);
}

// ---------------------------------------------------------------- single-block power iteration on the 21x21 support
// S_1 = 1024*T(:,DC) has 9 nonzeros; T couples +-1 cell/application, so after
// 10 applications the support is <= +-10. The full power chain (init + 9
// normalized sweeps + op-norm finalization) runs in one block on a 25x25
// wrapped patch. Arithmetic per nonzero cell is identical to the full-grid
// version (same fmaf tap order, same fp16 weights, same eps chain).
__global__ __launch_bounds__(256) void k_power(const __half* __restrict__ WpH,
                                               const float* __restrict__ wraw,
                                               float* __restrict__ t){
  __shared__ float Wp5[5][25][25];   // wrapped weight window, offsets -12..+12
  __shared__ float Fa[25][25], Fb[25][25];
  __shared__ float red[8];
  int tid=threadIdx.x;
  // stage weights (grid coord = (patch+1012)&1023)
  for(int idx=tid; idx<3125; idx+=256){
    int d=idx/625, rem=idx-d*625, pr=rem/25, pc=rem-(rem/25)*25;
    int gr=(pr+1012)&1023, gc=(pc+1012)&1023;
    Wp5[d][pr][pc]=__half2float(WpH[(size_t)d*HW_+((size_t)gr<<10)+gc]);
  }
  for(int idx=tid; idx<625; idx+=256){
    int pr=idx/25, pc=idx-(idx/25)*25;
    Fa[pr][pc]=0.f; Fb[pr][pc]=0.f;
  }
  __syncthreads();
  // init: S_1 = 1024*T(:,DC)  (9 entries around center 12,12)
  if (tid==0){
    float bb=0.f, v;
    v=1024.f*Wp5[0][12][12]; Fa[12][12]=v; bb=fmaf(v,v,bb);   // ( 0, 0)
    v=1024.f*Wp5[1][12][12]; Fa[12][13]=v; bb=fmaf(v,v,bb);   // ( 0, 1)
    v=1024.f*Wp5[1][12][11]; Fa[12][11]=v; bb=fmaf(v,v,bb);   // ( 0,-1)
    v=1024.f*Wp5[2][12][12]; Fa[13][12]=v; bb=fmaf(v,v,bb);   // ( 1, 0)
    v=1024.f*Wp5[3][12][12]; Fa[13][13]=v; bb=fmaf(v,v,bb);   // ( 1, 1)
    v=1024.f*Wp5[4][12][12]; Fa[13][11]=v; bb=fmaf(v,v,bb);   // ( 1,-1)
    v=1024.f*Wp5[2][11][12]; Fa[11][12]=v; bb=fmaf(v,v,bb);   // (-1, 0)
    v=1024.f*Wp5[4][11][13]; Fa[11][13]=v; bb=fmaf(v,v,bb);   // (-1, 1)
    v=1024.f*Wp5[3][11][11]; Fa[11][11]=v; bb=fmaf(v,v,bb);   // (-1,-1)
    red[0]=bb;
  }
  __syncthreads();
  float b=red[0];
  float (*cur)[25]=Fa, (*nxt)[25]=Fb;
  int lane=tid&63, wid=tid>>6;
  for(int n=0;n<9;n++){
    float sc=1.f/(sqrtf(b)+1e-12f);
    float dot=0.f, nsq=0.f;
    for(int idx=tid; idx<441; idx+=256){
      int pr=2+idx/21, pc=2+(idx-(idx/21)*21);
      float u = Wp5[0][pr][pc]*cur[pr][pc];
      u=fmaf(Wp5[1][pr][pc  ],cur[pr  ][pc+1],u);
      u=fmaf(Wp5[1][pr][pc-1],cur[pr  ][pc-1],u);
      u=fmaf(Wp5[2][pr][pc  ],cur[pr+1][pc  ],u);
      u=fmaf(Wp5[2][pr-1][pc],cur[pr-1][pc  ],u);
      u=fmaf(Wp5[3][pr][pc  ],cur[pr+1][pc+1],u);
      u=fmaf(Wp5[3][pr-1][pc-1],cur[pr-1][pc-1],u);
      u=fmaf(Wp5[4][pr][pc  ],cur[pr+1][pc-1],u);
      u=fmaf(Wp5[4][pr-1][pc+1],cur[pr-1][pc+1],u);
      dot=fmaf(cur[pr][pc],u,dot);
      float o=u*sc;
      nsq=fmaf(o,o,nsq);
      nxt[pr][pc]=o;
    }
    for(int o=32;o>0;o>>=1){ dot+=__shfl_down(dot,o,64); nsq+=__shfl_down(nsq,o,64); }
    __syncthreads();                 // tap reads + prior red reads complete
    if(lane==0){ red[wid]=nsq; red[4+wid]=dot; }
    __syncthreads();
    if(tid==0){
      float nsum=red[0]+red[1]+red[2]+red[3];
      float dsum=red[4]+red[5]+red[6]+red[7];
      if (n==8){
        float a=sc*sc*dsum;          // ||av_10||^2
        float vn=sqrtf(b)*sc;        // ||v_9||
        float opn=sqrtf(a)/(vn+1e-12f);
        float sig=1.f/(1.f+__expf(-wraw[0]));
        t[19]=2.f*sig/(opn*opn);
      }
      red[0]=nsum;
    }
    __syncthreads();
    b=red[0];
    float (*tmp)[25]=cur; cur=nxt; nxt=tmp;
  }
}

// ---------------------------------------------------------------- npcg: G2_row = rowIFFT( T*F - Gy ), block = k-grid row
__global__ __launch_bounds__(256) void k_Tsub_fft(const float2* __restrict__ Fin,
    const __half* __restrict__ WpH, const __half2* __restrict__ GyH,
    float2* __restrict__ G2, float scale){
  __shared__ __align__(16) float2 Fsm[3][1024];   // reused as FFT scratch A|B after taps
  int r=blockIdx.x, tid=threadIdx.x;
  int rm=(r+1023)&1023, rp=(r+1)&1023;
  {
    const float4* s0=(const float4*)(Fin+((size_t)rm<<10));
    const float4* s1=(const float4*)(Fin+((size_t)r <<10));
    const float4* s2=(const float4*)(Fin+((size_t)rp<<10));
    float4* f0=(float4*)Fsm[0]; float4* f1=(float4*)Fsm[1]; float4* f2=(float4*)Fsm[2];
    for(int p2=tid;p2<512;p2+=256){ f0[p2]=s0[p2]; f1[p2]=s1[p2]; f2[p2]=s2[p2]; }
  }
  __syncthreads();
  int rowW=r<<10, rowWm=rm<<10;
  float2 v[4];
  const __half2* gyr=GyH+((size_t)r<<10);
#pragma unroll
  for(int q=0;q<4;q++){
    int c=tid+256*q;
    float2 u=t_tap(&Fsm[0][0],&Fsm[1][0],&Fsm[2][0],WpH,rowW,rowWm,c);
    float2 gy=__half22float2(gyr[c]);
    v[q]=make_float2(u.x-gy.x,u.y-gy.y);   // note: c = tid+256q IS the fft1024_core input layout
  }
  __syncthreads();                          // all Fsm reads done before aliasing
  float2* A=(float2*)Fsm; float2* B=A+1088;
  fft1024_core<1>(v,tid,A,B,scale);
  float2* d=G2+((size_t)r<<10);
#pragma unroll
  for(int rr=0;rr<4;rr++) d[tid+256*rr]=v[rr];
}

// ---------------------------------------------------------------- fused 5x5 composed CNN + update
// blocks 0..1023: interior tiles (skip border pixels); blocks 1024..1039: border ring
#define CT_S 41
__global__ __launch_bounds__(256) void k_cnn5(const float2* __restrict__ x, const float2* __restrict__ res,
    const float* __restrict__ ec, const float* __restrict__ t,
    float2* __restrict__ xout, float* __restrict__ outPlanar){
  int tid=threadIdx.x;
  if (blockIdx.x>=1024){
    // ---- border ring: exact conv2(conv1) with h zero-masked outside image
    int id = (blockIdx.x-1024)*256+tid;   // 4096
    int py,px;
    if (id<1024){ py=0; px=id; }
    else if(id<2048){ py=1023; px=id-1024; }
    else if(id<3072){ py=id-2048; px=0; }
    else { py=id-3072; px=1023; }
    float s0=ec[444], s1=ec[445];
    for(int uy=0;uy<3;uy++){
      int qy=py+uy-1; if((unsigned)qy>=1024u) continue;
      for(int ux=0;ux<3;ux++){
        int qx=px+ux-1; if((unsigned)qx>=1024u) continue;
        int u=uy*3+ux;
        s0+=ec[102+u]; s1+=ec[111+u];
        const float* B0=&ec[120+u*18];
        const float* B1=&ec[282+u*18];
        for(int vy=0;vy<3;vy++){
          int sy2=qy+vy-1; if((unsigned)sy2>=1024u) continue;
          for(int vx=0;vx<3;vx++){
            int sx2=qx+vx-1; if((unsigned)sx2>=1024u) continue;
            int v=vy*3+vx;
            float2 xv=x[(size_t)sy2*W_+sx2];
            s0 = fmaf(B0[v],xv.x,fmaf(B0[9+v],xv.y,s0));
            s1 = fmaf(B1[v],xv.x,fmaf(B1[9+v],xv.y,s1));
          }
        }
      }
    }
    float wreg=t[19];
    size_t base=(size_t)py*W_+px;
    float2 xv=x[base], rv=res[base];
    float o0=xv.x - wreg*rv.x - s0;
    float o1=xv.y - wreg*rv.y - s1;
    if (outPlanar){ outPlanar[base]=o0; outPlanar[HW_+base]=o1; }
    else          { xout[base]=make_float2(o0,o1); }
    return;
  }
  __shared__ float xt0[36*CT_S];
  __shared__ float xt1[36*CT_S];
  __shared__ float sE[102];
  int by=blockIdx.x>>5, bx=blockIdx.x&31;
  int ty0=by<<5, tx0=bx<<5;
  for(int p=tid;p<102;p+=256) sE[p]=ec[p];
  for(int p=tid;p<1296;p+=256){
    int r=p/36, c=p-r*36;
    int gy=ty0-2+r, gx=tx0-2+c;
    float vx=0.f, vy=0.f;
    if((unsigned)gy<1024u && (unsigned)gx<1024u){ float2 v=x[(size_t)gy*W_+gx]; vx=v.x; vy=v.y; }
    xt0[r*CT_S+c]=vx; xt1[r*CT_S+c]=vy;
  }
  __syncthreads();
  int row=tid>>3, c4=(tid&7)<<2;
  float a0[4], a1[4];
  float C00=sE[100], C01=sE[101];
#pragma unroll
  for(int jj=0;jj<4;jj++){ a0[jj]=C00; a1[jj]=C01; }
#pragma unroll
  for(int dy=0;dy<5;dy++){
    const float* r0=&xt0[(row+dy)*CT_S+c4];
    const float* r1=&xt1[(row+dy)*CT_S+c4];
    float f0[9], f1[9];
#pragma unroll
    for(int q=0;q<9;q++){ f0[q]=r0[q]; f1[q]=r1[q]; }
#pragma unroll
    for(int dx=0;dx<5;dx++){
      float e00=sE[dy*5+dx], e01=sE[25+dy*5+dx];
      float e10=sE[50+dy*5+dx], e11=sE[75+dy*5+dx];
#pragma unroll
      for(int jj=0;jj<4;jj++){
        a0[jj]=fmaf(e00,f0[jj+dx],fmaf(e01,f1[jj+dx],a0[jj]));
        a1[jj]=fmaf(e10,f0[jj+dx],fmaf(e11,f1[jj+dx],a1[jj]));
      }
    }
  }
  int py=ty0+row;
  float wreg = t[19];
  size_t base=(size_t)py*W_ + tx0 + c4;
  bool rowEdge = (py==0)||(py==1023);
  if (outPlanar){
#pragma unroll
    for(int jj=0;jj<4;jj++){
      int px=tx0+c4+jj;
      if (rowEdge || px==0 || px==1023) continue;   // ring blocks own these
      float2 rv=res[base+jj];
      float xr_=xt0[(row+2)*CT_S+c4+jj+2];
      float xi_=xt1[(row+2)*CT_S+c4+jj+2];
      outPlanar[base+jj]      = xr_ - wreg*rv.x - a0[jj];
      outPlanar[HW_+base+jj]  = xi_ - wreg*rv.y - a1[jj];
    }
  } else {
#pragma unroll
    for(int jj=0;jj<4;jj++){
      int px=tx0+c4+jj;
      if (rowEdge || px==0 || px==1023) continue;
      float2 rv=res[base+jj];
      float xr_=xt0[(row+2)*CT_S+c4+jj+2];
      float xi_=xt1[(row+2)*CT_S+c4+jj+2];
      xout[base+jj]=make_float2(xr_ - wreg*rv.x - a0[jj],
                                xi_ - wreg*rv.y - a1[jj]);
    }
  }
}

// ================================================================ launch
extern "C" void kernel_launch(void* const* d_in, const int* in_sizes, int n_in,
                              void* d_out, int out_size, void* d_ws, size_t ws_size,
                              hipStream_t stream){
  (void)in_sizes; (void)n_in; (void)out_size; (void)ws_size;
  const float* xr  =(const float*)d_in[0];
  const float* xi  =(const float*)d_in[1];
  const float* kre =(const float*)d_in[2];
  const float* kim =(const float*)d_in[3];
  const float* kt  =(const float*)d_in[4];
  const float* wraw=(const float*)d_in[5];
  const float* w1  =(const float*)d_in[6];
  const float* b1  =(const float*)d_in[7];
  const float* w2  =(const float*)d_in[8];
  const float* b2  =(const float*)d_in[9];
  float* out = (float*)d_out;

  char* ws=(char*)d_ws;
  float2* Wx0 =(float2*)(ws);                      // 8MB
  float2* Wx1 =(float2*)(ws + ((size_t) 8<<20));   // 8MB
  float2* WF  =(float2*)(ws + ((size_t)16<<20));   // 8MB  fwd-FFT grid (npcg)
  float2* G2  =(float2*)(ws + ((size_t)24<<20));   // 8MB  npcg residual grid
  float* Wacc =(float*) (ws + ((size_t)32<<20));   // 20MB 5 fp32 accum planes
  float2* GyAcc=(float2*)(ws + ((size_t)52<<20));  // 8MB  fp32 Gy' accum (contiguous with Wacc)
  __half* WpH =(__half*)(ws + ((size_t)60<<20));   // 10MB 5 stencil planes (fp16)
  __half2* GyH=(__half2*)(ws + ((size_t)70<<20));  // 4MB  Gy fp16
  float* t    =(float*) (ws + ((size_t)74<<20) + 8192);
  float* ec   =(float*) (ws + ((size_t)74<<20) + 16384);
  const float SC = 0.03125f;   // 1/32 per 1-D ortho pass

  // ---- setup: pack/zero -> direct atomic plane build -> fp16 convert
  k_pack<<<HW_/256+1,256,0,stream>>>(xr,xi,Wx0,t,Wacc,w1,b1,w2,b2,ec);
  k_build<<<M_/256,256,0,stream>>>(kt,kre,kim,Wacc,GyAcc,t);
  k_convert<<<HW_/256,256,0,stream>>>(Wacc,GyAcc,WpH,GyH,t);

  // ---- full power iteration + op-norm finalization in ONE single-block kernel
  k_power<<<1,256,0,stream>>>(WpH,wraw,t);

  // ---- npcg = 4 PGD iterations
  for (int it=0; it<4; it++){
    float2* xin  = (it&1)? Wx1 : Wx0;
    float2* xout = (it&1)? Wx0 : Wx1;
    float* planar = (it==3)? out : (float*)nullptr;
    k_fft_rows<-1><<<H_,256,0,stream>>>(xin,WF,SC);
    k_fft_cols1<-1><<<H_,256,0,stream>>>(WF,SC);
    k_Tsub_fft<<<H_,256,0,stream>>>(WF,WpH,GyH,G2,SC);
    k_fft_cols1<1><<<H_,256,0,stream>>>(G2,SC);
    k_cnn5<<<1040,256,0,stream>>>(xin,G2,ec,t,xout,planar);
  }
}

// Round 12
// 398.049 us; speedup vs baseline: 2.0571x; 2.0571x over previous
//
#include <hip/hip_runtime.h>
#include <hip/hip_fp16.h>

#define H_  1024
#define W_  1024
#define HW_ (H_*W_)
#define M_  524288

#define SWZ(a) ((a) + ((a)>>4))

// ---------------------------------------------------------------- complex mul
__device__ __forceinline__ float2 cmulf(float2 a, float2 b){
  return make_float2(fmaf(a.x,b.x,-(a.y*b.y)), fmaf(a.x,b.y,a.y*b.x));
}

// ---------------------------------------------------------------- radix-4 bfly
template<int DIR>
__device__ __forceinline__ void bfly4(float2 v[4], int j, int Ns){
  if (Ns>1){
    float ang = ((DIR>0)?6.28318530717958647692f:-6.28318530717958647692f)
                * (float)(j&(Ns-1)) / (float)(4*Ns);
    float s,c; __sincosf(ang,&s,&c);
    float2 w1=make_float2(c,s);
    float2 w2=cmulf(w1,w1);
    float2 w3=cmulf(w2,w1);
    v[1]=cmulf(v[1],w1); v[2]=cmulf(v[2],w2); v[3]=cmulf(v[3],w3);
  }
  float2 t0=make_float2(v[0].x+v[2].x, v[0].y+v[2].y);
  float2 t2=make_float2(v[0].x-v[2].x, v[0].y-v[2].y);
  float2 t1=make_float2(v[1].x+v[3].x, v[1].y+v[3].y);
  float2 t3=make_float2(v[1].x-v[3].x, v[1].y-v[3].y);
  float2 t3r=(DIR<0)?make_float2(t3.y,-t3.x):make_float2(-t3.y,t3.x);
  v[0]=make_float2(t0.x+t1.x,  t0.y+t1.y);
  v[1]=make_float2(t2.x+t3r.x, t2.y+t3r.y);
  v[2]=make_float2(t0.x-t1.x,  t0.y-t1.y);
  v[3]=make_float2(t2.x-t3r.x, t2.y-t3r.y);
}

template<int DIR, int NS>
__device__ __forceinline__ void fft_stage(int j, const float2* src, float2* dst){
  float2 v[4];
#pragma unroll
  for(int r=0;r<4;r++) v[r]=src[SWZ(j+256*r)];
  bfly4<DIR>(v,j,NS);
  int base = ((j & ~(NS-1))<<2) | (j&(NS-1));
#pragma unroll
  for(int r=0;r<4;r++) dst[SWZ(base+NS*r)]=v[r];
}

template<int DIR>
__device__ __forceinline__ void fft1024_core(float2 v[4], int j, float2* A, float2* B, float scale){
  bfly4<DIR>(v,j,1);
#pragma unroll
  for(int r=0;r<4;r++) A[SWZ(4*j+r)]=v[r];
  __syncthreads();
  fft_stage<DIR,4 >(j,A,B); __syncthreads();
  fft_stage<DIR,16>(j,B,A); __syncthreads();
  fft_stage<DIR,64>(j,A,B); __syncthreads();
#pragma unroll
  for(int r=0;r<4;r++) v[r]=B[SWZ(j+256*r)];
  bfly4<DIR>(v,j,256);
#pragma unroll
  for(int r=0;r<4;r++){ v[r].x*=scale; v[r].y*=scale; }
}

template<int DIR>
__global__ __launch_bounds__(256) void k_fft_rows(const float2* src, float2* dst, float scale){
  __shared__ float2 A[1088], B[1088];
  int j = threadIdx.x;
  const float2* s = src + (size_t)blockIdx.x*W_;
  float2 v[4];
#pragma unroll
  for(int r=0;r<4;r++) v[r]=s[j+256*r];
  fft1024_core<DIR>(v,j,A,B,scale);
  float2* d = dst + (size_t)blockIdx.x*W_;
#pragma unroll
  for(int r=0;r<4;r++) d[j+256*r]=v[r];
}

// 1 column per block, registers-direct; XCD-aware column swizzle so the 8
// columns sharing each 64B line live on one XCD's L2.
template<int DIR>
__global__ __launch_bounds__(256) void k_fft_cols1(float2* data, float scale){
  __shared__ float2 A[1088], B[1088];
  int tid=threadIdx.x;
  int col = ((blockIdx.x&7)<<7) + (blockIdx.x>>3);
  float2 v[4];
#pragma unroll
  for(int r=0;r<4;r++) v[r]=data[(size_t)(tid+256*r)*W_ + col];
  fft1024_core<DIR>(v,tid,A,B,scale);
#pragma unroll
  for(int r=0;r<4;r++) data[(size_t)(tid+256*r)*W_ + col]=v[r];
}

// ---------------------------------------------------------------- init: pack x, zero counts, zero t; block 4096 builds conv tables
// ec layout (floats): [0..99] E[oc*50+ic*25+dy*5+dx]; [100..101] C0;
// [102..119] Bb[oc*9+u]; [120..443] Btab[oc*162+u*18+ic*9+v]; [444..445] b2
__global__ __launch_bounds__(256) void k_pack(const float* xr, const float* xi, float2* X, float* t,
                                              int* counts,
                                              const float* w1, const float* b1,
                                              const float* w2, const float* b2, float* ec){
  __shared__ float sw1[576], sw2[576], sb1[32], sB[324];
  int tid=threadIdx.x;
  if (blockIdx.x==4096){
    for(int p=tid;p<576;p+=256){ sw1[p]=w1[p]; sw2[p]=w2[p]; }
    if(tid<32) sb1[tid]=b1[tid];
    __syncthreads();
    for(int e=tid;e<324;e+=256){
      int oc=e/162, r=e-oc*162, u=r/18, r2=r-u*18, ic=r2/9, v=r2-ic*9;
      float s=0.f;
      for(int cm=0;cm<32;cm++) s=fmaf(sw2[oc*288+cm*9+u], sw1[cm*18+ic*9+v], s);
      sB[e]=s; ec[120+e]=s;
    }
    if(tid<18){
      int oc=tid/9, u=tid-oc*9;
      float s=0.f;
      for(int cm=0;cm<32;cm++) s=fmaf(sw2[oc*288+cm*9+u], sb1[cm], s);
      ec[102+tid]=s;
    }
    if(tid<2){
      float s=b2[tid];
      for(int u=0;u<9;u++){
        float bb=0.f;
        for(int cm=0;cm<32;cm++) bb=fmaf(sw2[tid*288+cm*9+u], sb1[cm], bb);
        s+=bb;
      }
      ec[100+tid]=s;
      ec[444+tid]=b2[tid];
    }
    __syncthreads();
    if(tid<100){
      int oc=tid/50, r=tid-oc*50, ic=r/25, r2=r-ic*25, dy=r2/5, dx=r2-dy*5;
      float s=0.f;
      for(int uy=0;uy<3;uy++){ int vy=dy-uy; if(vy<0||vy>2) continue;
        for(int ux=0;ux<3;ux++){ int vx=dx-ux; if(vx<0||vx>2) continue;
          s+=sB[oc*162+(uy*3+ux)*18+ic*9+vy*3+vx];
        }
      }
      ec[tid]=s;
    }
    return;
  }
  int i = blockIdx.x*256+tid;
  X[i]=make_float2(xr[i],xi[i]);
  counts[i]=0;
  if (blockIdx.x==0 && tid<32) t[tid]=0.f;
}

__global__ __launch_bounds__(256) void k_hist(const float* kt, int* counts, float* pmax){
  int m = blockIdx.x*256+threadIdx.x;
  float r = 0.f;
  {
    float kx=kt[2*m], ky=kt[2*m+1];
    float dx=kx-0.5f, dy=ky-0.5f;
    r = sqrtf(dx*dx+dy*dy);
    int ix = ((int)floorf(kx*1024.f))&1023;
    int iy = ((int)floorf(ky*1024.f))&1023;
    atomicAdd(&counts[(ix<<10)|iy],1);
  }
  for(int o=32;o>0;o>>=1) r = fmaxf(r, __shfl_down(r,o,64));
  __shared__ float sm[4];
  if((threadIdx.x&63)==0) sm[threadIdx.x>>6]=r;
  __syncthreads();
  if(threadIdx.x==0)
    pmax[blockIdx.x] = fmaxf(fmaxf(sm[0],sm[1]),fmaxf(sm[2],sm[3]));
}

// ---------------------------------------------------------------- scan (per-row-local offsets; bsum holds row bases)
// block 1024: fused global max-radius reduction (pmax -> t[15])
__global__ __launch_bounds__(256) void k_scan1(const int* cnt, int* off, int* bsum,
                                               const float* pmax, float* t){
  int tid = threadIdx.x;
  if (blockIdx.x>=1024){
    float s=-1e30f;
    for(int k=tid;k<2048;k+=256) s=fmaxf(s,pmax[k]);
    __shared__ float smx[4];
    for(int o=32;o>0;o>>=1) s=fmaxf(s,__shfl_down(s,o,64));
    if((tid&63)==0) smx[tid>>6]=s;
    __syncthreads();
    if(tid==0) t[15]=fmaxf(fmaxf(smx[0],smx[1]),fmaxf(smx[2],smx[3]));
    return;
  }
  __shared__ int sm[256];
  int base = blockIdx.x*1024;
  int4 c = *(const int4*)(cnt + base + tid*4);
  int s = c.x+c.y+c.z+c.w;
  sm[tid]=s; __syncthreads();
  int v=s;
  for(int o=1;o<256;o<<=1){
    int u = (tid>=o)? sm[tid-o]:0;
    __syncthreads();
    v += u; sm[tid]=v;
    __syncthreads();
  }
  int excl = v - s;
  int4 o4;
  o4.x=excl; o4.y=excl+c.x; o4.z=excl+c.x+c.y; o4.w=excl+c.x+c.y+c.z;
  *(int4*)(off+base+tid*4)=o4;
  if (tid==255) bsum[blockIdx.x]=v;
}

__global__ __launch_bounds__(256) void k_scan2(int* bsum){
  __shared__ int sm[256];
  int tid=threadIdx.x;
  int4 c = *(const int4*)(bsum + tid*4);
  int s = c.x+c.y+c.z+c.w;
  sm[tid]=s; __syncthreads();
  int v=s;
  for(int o=1;o<256;o<<=1){
    int u = (tid>=o)? sm[tid-o]:0;
    __syncthreads();
    v += u; sm[tid]=v;
    __syncthreads();
  }
  int excl=v-s;
  int4 o4;
  o4.x=excl; o4.y=excl+c.x; o4.z=excl+c.x+c.y; o4.w=excl+c.x+c.y+c.z;
  *(int4*)(bsum+tid*4)=o4;
}

// ---------------------------------------------------------------- fused reorder: cell place + dcf + pd write (global pos = local + bsum[row])
// pd[p] = (tx, ty, y_dcf.x, y_dcf.y)  (sorted-by-cell point data)
__global__ __launch_bounds__(256) void k_reorder12(const float* __restrict__ kt,
                                                   const float* __restrict__ kre,
                                                   const float* __restrict__ kim,
                                                   int* __restrict__ off,
                                                   const int* __restrict__ bsum,
                                                   float4* __restrict__ pd,
                                                   const float* __restrict__ t){
  int m = blockIdx.x*256+threadIdx.x;
  float kx=kt[2*m], ky=kt[2*m+1];
  float gx=kx*1024.f, gy=ky*1024.f;
  float fx=floorf(gx), fy=floorf(gy);
  float tx=gx-fx, ty=gy-fy;
  int ix=((int)fx)&1023, iy=((int)fy)&1023;
  int pos = atomicAdd(&off[(ix<<10)|iy],1) + bsum[ix];
  float dx=kx-0.5f, dy=ky-0.5f;
  float r=sqrtf(dx*dx+dy*dy);
  float dcf=sqrtf(r/(t[15]+1e-8f));
  pd[pos]=make_float4(tx,ty,kre[m]*dcf,kim[m]*dcf);
}

// ---------------------------------------------------------------- half-pack helper
__device__ __forceinline__ void store_h4(__half* dst, const float v[4]){
  __half h0=__float2half(v[0]), h1=__float2half(v[1]),
         h2=__float2half(v[2]), h3=__float2half(v[3]);
  short4 s;
  s.x=*(short*)&h0; s.y=*(short*)&h1; s.z=*(short*)&h2; s.w=*(short*)&h3;
  *(short4*)dst=s;
}

// ---------------------------------------------------------------- build T = Grid∘Sample as 5 symmetric stencil planes (fp16)
// + Gy = Grid(y*sqrt_dcf) (fp16) in the same CSR walk. Offsets are row-local + bsum[row].
// Wd[c] = T[c][c+d] = sum_p w_p(c)*w_p(c+d), d in {(0,0),(0,1),(1,0),(1,1),(1,-1)}
__global__ __launch_bounds__(256) void k_mkWG(const float4* __restrict__ pd,
                                              const int* __restrict__ off,
                                              const int* __restrict__ bsum,
                                              __half* __restrict__ WpH,
                                              __half2* __restrict__ GyH){
  int gid=blockIdx.x*256+threadIdx.x;
  int r=gid>>8, c0=(gid&255)<<2;
  float w00[4],wE[4],wS[4],wSE[4],wSW[4],gx[4],gy[4];
#pragma unroll
  for(int q=0;q<4;q++){ w00[q]=0.f;wE[q]=0.f;wS[q]=0.f;wSE[q]=0.f;wSW[q]=0.f;gx[q]=0.f;gy[q]=0.f; }
#pragma unroll
  for(int dr=0;dr<2;dr++){
    int br=(r-dr)&1023;
    int rowbase=br<<10;
    int rb=bsum[br];
    if (c0>0){
      int O[6];
#pragma unroll
      for(int q=0;q<6;q++) O[q]=off[rowbase+c0-2+q]+rb;
#pragma unroll
      for(int i=0;i<5;i++){
        for(int j=O[i]; j<O[i+1]; j++){
          float4 p=pd[j];
          float wx = dr? p.x : 1.f-p.x;
          float uy=1.f-p.y, vy=p.y;
          float a0=wx*uy, a1=wx*vy;          // weights at cols pc, pc+1 (this cell row)
          float wpu=p.x*uy, wpv=p.x*vy;      // partner-row (r+1) weights (valid when dr==0)
          if (i>=1){                          // B=0 cell (col = pc) at slot i-1
            w00[i-1]=fmaf(a0,a0,w00[i-1]);
            wE [i-1]=fmaf(a0,a1,wE [i-1]);
            gx [i-1]=fmaf(a0,p.z,gx[i-1]); gy[i-1]=fmaf(a0,p.w,gy[i-1]);
            if(!dr){ wS[i-1]=fmaf(a0,wpu,wS[i-1]); wSE[i-1]=fmaf(a0,wpv,wSE[i-1]); }
          }
          if (i<=3){                          // B=1 cell (col = pc+1) at slot i
            w00[i]=fmaf(a1,a1,w00[i]);
            gx [i]=fmaf(a1,p.z,gx[i]); gy[i]=fmaf(a1,p.w,gy[i]);
            if(!dr){ wS[i]=fmaf(a1,wpv,wS[i]); wSW[i]=fmaf(a1,wpu,wSW[i]); }
          }
        }
      }
    } else {
      int bw=rowbase+1023;
      int sw=off[bw-1]+rb, ew=off[bw]+rb;
      for(int j=sw;j<ew;j++){                 // wrap: cell col 1023's points, B=1 at slot 0
        float4 p=pd[j];
        float wx = dr? p.x : 1.f-p.x;
        float uy=1.f-p.y, vy=p.y;
        float a1=wx*vy;
        w00[0]=fmaf(a1,a1,w00[0]);
        gx [0]=fmaf(a1,p.z,gx[0]); gy[0]=fmaf(a1,p.w,gy[0]);
        if(!dr){ float wpu=p.x*uy, wpv=p.x*vy;
          wS[0]=fmaf(a1,wpv,wS[0]); wSW[0]=fmaf(a1,wpu,wSW[0]); }
      }
      int O[5];
      O[0]=rb;                                // row start
#pragma unroll
      for(int q=1;q<5;q++) O[q]=off[rowbase+q-1]+rb;
#pragma unroll
      for(int i=0;i<4;i++){
        for(int j=O[i]; j<O[i+1]; j++){
          float4 p=pd[j];
          float wx = dr? p.x : 1.f-p.x;
          float uy=1.f-p.y, vy=p.y;
          float a0=wx*uy, a1=wx*vy;
          float wpu=p.x*uy, wpv=p.x*vy;
          w00[i]=fmaf(a0,a0,w00[i]);
          wE [i]=fmaf(a0,a1,wE [i]);
          gx [i]=fmaf(a0,p.z,gx[i]); gy[i]=fmaf(a0,p.w,gy[i]);
          if(!dr){ wS[i]=fmaf(a0,wpu,wS[i]); wSE[i]=fmaf(a0,wpv,wSE[i]); }
          if (i<=2){
            w00[i+1]=fmaf(a1,a1,w00[i+1]);
            gx [i+1]=fmaf(a1,p.z,gx[i+1]); gy[i+1]=fmaf(a1,p.w,gy[i+1]);
            if(!dr){ wS[i+1]=fmaf(a1,wpv,wS[i+1]); wSW[i+1]=fmaf(a1,wpu,wSW[i+1]); }
          }
        }
      }
    }
  }
  size_t base=((size_t)r<<10)+c0;
  store_h4(&WpH[base],               w00);
  store_h4(&WpH[(size_t)HW_+base],   wE );
  store_h4(&WpH[(size_t)2*HW_+base], wS );
  store_h4(&WpH[(size_t)3*HW_+base], wSE);
  store_h4(&WpH[(size_t)4*HW_+base], wSW);
#pragma unroll
  for(int q=0;q<4;q++) GyH[base+q]=__floats2half2_rn(gx[q],gy[q]);
}

// ---------------------------------------------------------------- 9-tap symmetric stencil, complex field (fp16 weights)
__device__ __forceinline__ float2 t_tap(const float2* __restrict__ Fm, const float2* __restrict__ F0,
                                        const float2* __restrict__ Fp, const __half* __restrict__ WpH,
                                        int rowW, int rowWm, int c){
  int cm=(c+1023)&1023, cp=(c+1)&1023;
  const __half* W00=WpH;
  const __half* WE =WpH+(size_t)HW_;
  const __half* WS =WpH+(size_t)2*HW_;
  const __half* WSE=WpH+(size_t)3*HW_;
  const __half* WSW=WpH+(size_t)4*HW_;
  float2 f=F0[c];
  float w=__half2float(W00[rowW+c]);
  float ux=w*f.x, uy=w*f.y;
  f=F0[cp]; w=__half2float(WE [rowW +c ]); ux=fmaf(w,f.x,ux); uy=fmaf(w,f.y,uy);  // +E
  f=F0[cm]; w=__half2float(WE [rowW +cm]); ux=fmaf(w,f.x,ux); uy=fmaf(w,f.y,uy);  // -E
  f=Fp[c ]; w=__half2float(WS [rowW +c ]); ux=fmaf(w,f.x,ux); uy=fmaf(w,f.y,uy);  // +S
  f=Fm[c ]; w=__half2float(WS [rowWm+c ]); ux=fmaf(w,f.x,ux); uy=fmaf(w,f.y,uy);  // -S
  f=Fp[cp]; w=__half2float(WSE[rowW +c ]); ux=fmaf(w,f.x,ux); uy=fmaf(w,f.y,uy);  // +SE
  f=Fm[cm]; w=__half2float(WSE[rowWm+cm]); ux=fmaf(w,f.x,ux); uy=fmaf(w,f.y,uy);  // -SE
  f=Fp[cm]; w=__half2float(WSW[rowW +c ]); ux=fmaf(w,f.x,ux); uy=fmaf(w,f.y,uy);  // +SW
  f=Fm[cp]; w=__half2float(WSW[rowWm+cp]); ux=fmaf(w,f.x,ux); uy=fmaf(w,f.y,uy);  // -SW
  return make_float2(ux,uy);
}

// ---------------------------------------------------------------- single-block power iteration on the 21x21 support
// S_1 = 1024*T(:,DC) has 9 nonzeros; T couples +-1 cell/application, so after
// 10 applications the support is <= +-10. The full power chain (init + 9
// normalized sweeps + op-norm finalization) runs in one block on a 25x25
// wrapped patch. Arithmetic per nonzero cell is identical to the full-grid
// version (same fmaf tap order, same fp16 weights, same eps chain).
__global__ __launch_bounds__(256) void k_power(const __half* __restrict__ WpH,
                                               const float* __restrict__ wraw,
                                               float* __restrict__ t){
  __shared__ float Wp5[5][25][25];   // wrapped weight window, offsets -12..+12
  __shared__ float Fa[25][25], Fb[25][25];
  __shared__ float red[8];
  int tid=threadIdx.x;
  // stage weights (grid coord = (patch+1012)&1023)
  for(int idx=tid; idx<3125; idx+=256){
    int d=idx/625, rem=idx-d*625, pr=rem/25, pc=rem-(rem/25)*25;
    int gr=(pr+1012)&1023, gc=(pc+1012)&1023;
    Wp5[d][pr][pc]=__half2float(WpH[(size_t)d*HW_+((size_t)gr<<10)+gc]);
  }
  for(int idx=tid; idx<625; idx+=256){
    int pr=idx/25, pc=idx-(idx/25)*25;
    Fa[pr][pc]=0.f; Fb[pr][pc]=0.f;
  }
  __syncthreads();
  // init: S_1 = 1024*T(:,DC)  (9 entries around center 12,12)
  if (tid==0){
    float bb=0.f, v;
    v=1024.f*Wp5[0][12][12]; Fa[12][12]=v; bb=fmaf(v,v,bb);   // ( 0, 0)
    v=1024.f*Wp5[1][12][12]; Fa[12][13]=v; bb=fmaf(v,v,bb);   // ( 0, 1)
    v=1024.f*Wp5[1][12][11]; Fa[12][11]=v; bb=fmaf(v,v,bb);   // ( 0,-1)
    v=1024.f*Wp5[2][12][12]; Fa[13][12]=v; bb=fmaf(v,v,bb);   // ( 1, 0)
    v=1024.f*Wp5[3][12][12]; Fa[13][13]=v; bb=fmaf(v,v,bb);   // ( 1, 1)
    v=1024.f*Wp5[4][12][12]; Fa[13][11]=v; bb=fmaf(v,v,bb);   // ( 1,-1)
    v=1024.f*Wp5[2][11][12]; Fa[11][12]=v; bb=fmaf(v,v,bb);   // (-1, 0)
    v=1024.f*Wp5[4][11][13]; Fa[11][13]=v; bb=fmaf(v,v,bb);   // (-1, 1)
    v=1024.f*Wp5[3][11][11]; Fa[11][11]=v; bb=fmaf(v,v,bb);   // (-1,-1)
    red[0]=bb;
  }
  __syncthreads();
  float b=red[0];
  float (*cur)[25]=Fa, (*nxt)[25]=Fb;
  int lane=tid&63, wid=tid>>6;
  for(int n=0;n<9;n++){
    float sc=1.f/(sqrtf(b)+1e-12f);
    float dot=0.f, nsq=0.f;
    for(int idx=tid; idx<441; idx+=256){
      int pr=2+idx/21, pc=2+(idx-(idx/21)*21);
      float u = Wp5[0][pr][pc]*cur[pr][pc];
      u=fmaf(Wp5[1][pr][pc  ],cur[pr  ][pc+1],u);
      u=fmaf(Wp5[1][pr][pc-1],cur[pr  ][pc-1],u);
      u=fmaf(Wp5[2][pr][pc  ],cur[pr+1][pc  ],u);
      u=fmaf(Wp5[2][pr-1][pc],cur[pr-1][pc  ],u);
      u=fmaf(Wp5[3][pr][pc  ],cur[pr+1][pc+1],u);
      u=fmaf(Wp5[3][pr-1][pc-1],cur[pr-1][pc-1],u);
      u=fmaf(Wp5[4][pr][pc  ],cur[pr+1][pc-1],u);
      u=fmaf(Wp5[4][pr-1][pc+1],cur[pr-1][pc+1],u);
      dot=fmaf(cur[pr][pc],u,dot);
      float o=u*sc;
      nsq=fmaf(o,o,nsq);
      nxt[pr][pc]=o;
    }
    for(int o=32;o>0;o>>=1){ dot+=__shfl_down(dot,o,64); nsq+=__shfl_down(nsq,o,64); }
    __syncthreads();                 // tap reads + prior red reads complete
    if(lane==0){ red[wid]=nsq; red[4+wid]=dot; }
    __syncthreads();
    if(tid==0){
      float nsum=red[0]+red[1]+red[2]+red[3];
      float dsum=red[4]+red[5]+red[6]+red[7];
      if (n==8){
        float a=sc*sc*dsum;          // ||av_10||^2
        float vn=sqrtf(b)*sc;        // ||v_9||
        float opn=sqrtf(a)/(vn+1e-12f);
        float sig=1.f/(1.f+__expf(-wraw[0]));
        t[19]=2.f*sig/(opn*opn);
      }
      red[0]=nsum;
    }
    __syncthreads();
    b=red[0];
    float (*tmp)[25]=cur; cur=nxt; nxt=tmp;
  }
}

// ---------------------------------------------------------------- npcg: G2_row = rowIFFT( T*F - Gy ), block = k-grid row
__global__ __launch_bounds__(256) void k_Tsub_fft(const float2* __restrict__ Fin,
    const __half* __restrict__ WpH, const __half2* __restrict__ GyH,
    float2* __restrict__ G2, float scale){
  __shared__ __align__(16) float2 Fsm[3][1024];   // reused as FFT scratch A|B after taps
  int r=blockIdx.x, tid=threadIdx.x;
  int rm=(r+1023)&1023, rp=(r+1)&1023;
  {
    const float4* s0=(const float4*)(Fin+((size_t)rm<<10));
    const float4* s1=(const float4*)(Fin+((size_t)r <<10));
    const float4* s2=(const float4*)(Fin+((size_t)rp<<10));
    float4* f0=(float4*)Fsm[0]; float4* f1=(float4*)Fsm[1]; float4* f2=(float4*)Fsm[2];
    for(int p2=tid;p2<512;p2+=256){ f0[p2]=s0[p2]; f1[p2]=s1[p2]; f2[p2]=s2[p2]; }
  }
  __syncthreads();
  int rowW=r<<10, rowWm=rm<<10;
  float2 v[4];
  const __half2* gyr=GyH+((size_t)r<<10);
#pragma unroll
  for(int q=0;q<4;q++){
    int c=tid+256*q;
    float2 u=t_tap(&Fsm[0][0],&Fsm[1][0],&Fsm[2][0],WpH,rowW,rowWm,c);
    float2 gy=__half22float2(gyr[c]);
    v[q]=make_float2(u.x-gy.x,u.y-gy.y);   // note: c = tid+256q IS the fft1024_core input layout
  }
  __syncthreads();                          // all Fsm reads done before aliasing
  float2* A=(float2*)Fsm; float2* B=A+1088;
  fft1024_core<1>(v,tid,A,B,scale);
  float2* d=G2+((size_t)r<<10);
#pragma unroll
  for(int rr=0;rr<4;rr++) d[tid+256*rr]=v[rr];
}

// ---------------------------------------------------------------- fused 5x5 composed CNN + update
// blocks 0..1023: interior tiles (skip border pixels); blocks 1024..1039: border ring
#define CT_S 41
__global__ __launch_bounds__(256) void k_cnn5(const float2* __restrict__ x, const float2* __restrict__ res,
    const float* __restrict__ ec, const float* __restrict__ t,
    float2* __restrict__ xout, float* __restrict__ outPlanar){
  int tid=threadIdx.x;
  if (blockIdx.x>=1024){
    // ---- border ring: exact conv2(conv1) with h zero-masked outside image
    int id = (blockIdx.x-1024)*256+tid;   // 4096
    int py,px;
    if (id<1024){ py=0; px=id; }
    else if(id<2048){ py=1023; px=id-1024; }
    else if(id<3072){ py=id-2048; px=0; }
    else { py=id-3072; px=1023; }
    float s0=ec[444], s1=ec[445];
    for(int uy=0;uy<3;uy++){
      int qy=py+uy-1; if((unsigned)qy>=1024u) continue;
      for(int ux=0;ux<3;ux++){
        int qx=px+ux-1; if((unsigned)qx>=1024u) continue;
        int u=uy*3+ux;
        s0+=ec[102+u]; s1+=ec[111+u];
        const float* B0=&ec[120+u*18];
        const float* B1=&ec[282+u*18];
        for(int vy=0;vy<3;vy++){
          int sy2=qy+vy-1; if((unsigned)sy2>=1024u) continue;
          for(int vx=0;vx<3;vx++){
            int sx2=qx+vx-1; if((unsigned)sx2>=1024u) continue;
            int v=vy*3+vx;
            float2 xv=x[(size_t)sy2*W_+sx2];
            s0 = fmaf(B0[v],xv.x,fmaf(B0[9+v],xv.y,s0));
            s1 = fmaf(B1[v],xv.x,fmaf(B1[9+v],xv.y,s1));
          }
        }
      }
    }
    float wreg=t[19];
    size_t base=(size_t)py*W_+px;
    float2 xv=x[base], rv=res[base];
    float o0=xv.x - wreg*rv.x - s0;
    float o1=xv.y - wreg*rv.y - s1;
    if (outPlanar){ outPlanar[base]=o0; outPlanar[HW_+base]=o1; }
    else          { xout[base]=make_float2(o0,o1); }
    return;
  }
  __shared__ float xt0[36*CT_S];
  __shared__ float xt1[36*CT_S];
  __shared__ float sE[102];
  int by=blockIdx.x>>5, bx=blockIdx.x&31;
  int ty0=by<<5, tx0=bx<<5;
  for(int p=tid;p<102;p+=256) sE[p]=ec[p];
  for(int p=tid;p<1296;p+=256){
    int r=p/36, c=p-r*36;
    int gy=ty0-2+r, gx=tx0-2+c;
    float vx=0.f, vy=0.f;
    if((unsigned)gy<1024u && (unsigned)gx<1024u){ float2 v=x[(size_t)gy*W_+gx]; vx=v.x; vy=v.y; }
    xt0[r*CT_S+c]=vx; xt1[r*CT_S+c]=vy;
  }
  __syncthreads();
  int row=tid>>3, c4=(tid&7)<<2;
  float a0[4], a1[4];
  float C00=sE[100], C01=sE[101];
#pragma unroll
  for(int jj=0;jj<4;jj++){ a0[jj]=C00; a1[jj]=C01; }
#pragma unroll
  for(int dy=0;dy<5;dy++){
    const float* r0=&xt0[(row+dy)*CT_S+c4];
    const float* r1=&xt1[(row+dy)*CT_S+c4];
    float f0[9], f1[9];
#pragma unroll
    for(int q=0;q<9;q++){ f0[q]=r0[q]; f1[q]=r1[q]; }
#pragma unroll
    for(int dx=0;dx<5;dx++){
      float e00=sE[dy*5+dx], e01=sE[25+dy*5+dx];
      float e10=sE[50+dy*5+dx], e11=sE[75+dy*5+dx];
#pragma unroll
      for(int jj=0;jj<4;jj++){
        a0[jj]=fmaf(e00,f0[jj+dx],fmaf(e01,f1[jj+dx],a0[jj]));
        a1[jj]=fmaf(e10,f0[jj+dx],fmaf(e11,f1[jj+dx],a1[jj]));
      }
    }
  }
  int py=ty0+row;
  float wreg = t[19];
  size_t base=(size_t)py*W_ + tx0 + c4;
  bool rowEdge = (py==0)||(py==1023);
  if (outPlanar){
#pragma unroll
    for(int jj=0;jj<4;jj++){
      int px=tx0+c4+jj;
      if (rowEdge || px==0 || px==1023) continue;   // ring blocks own these
      float2 rv=res[base+jj];
      float xr_=xt0[(row+2)*CT_S+c4+jj+2];
      float xi_=xt1[(row+2)*CT_S+c4+jj+2];
      outPlanar[base+jj]      = xr_ - wreg*rv.x - a0[jj];
      outPlanar[HW_+base+jj]  = xi_ - wreg*rv.y - a1[jj];
    }
  } else {
#pragma unroll
    for(int jj=0;jj<4;jj++){
      int px=tx0+c4+jj;
      if (rowEdge || px==0 || px==1023) continue;
      float2 rv=res[base+jj];
      float xr_=xt0[(row+2)*CT_S+c4+jj+2];
      float xi_=xt1[(row+2)*CT_S+c4+jj+2];
      xout[base+jj]=make_float2(xr_ - wreg*rv.x - a0[jj],
                                xi_ - wreg*rv.y - a1[jj]);
    }
  }
}

// ================================================================ launch
extern "C" void kernel_launch(void* const* d_in, const int* in_sizes, int n_in,
                              void* d_out, int out_size, void* d_ws, size_t ws_size,
                              hipStream_t stream){
  (void)in_sizes; (void)n_in; (void)out_size; (void)ws_size;
  const float* xr  =(const float*)d_in[0];
  const float* xi  =(const float*)d_in[1];
  const float* kre =(const float*)d_in[2];
  const float* kim =(const float*)d_in[3];
  const float* kt  =(const float*)d_in[4];
  const float* wraw=(const float*)d_in[5];
  const float* w1  =(const float*)d_in[6];
  const float* b1  =(const float*)d_in[7];
  const float* w2  =(const float*)d_in[8];
  const float* b2  =(const float*)d_in[9];
  float* out = (float*)d_out;

  char* ws=(char*)d_ws;
  float2* Wx0 =(float2*)(ws);                      // 8MB
  float2* Wx1 =(float2*)(ws + ((size_t) 8<<20));   // 8MB
  int*   counts=(int*)  (ws + ((size_t) 8<<20));   // 4MB alias of Wx1 (setup only)
  float2* WF  =(float2*)(ws + ((size_t)16<<20));   // 8MB  fwd-FFT grid (npcg)
  float4* pd  =(float4*)(ws + ((size_t)24<<20));   // 8MB  (tx,ty,ydcf.x,ydcf.y) sorted
  float2* G2  =(float2*)(ws + ((size_t)32<<20));   // 8MB  npcg residual grid
  int*  off   =(int*)   (ws + ((size_t)40<<20));   // 4MB  CSR ends (row-local)
  __half2* GyH=(__half2*)(ws + ((size_t)44<<20));  // 4MB  Grid(y*sqrt_dcf) fp16
  __half* WpH =(__half*)(ws + ((size_t)52<<20));   // 10MB 5 stencil planes (fp16)
  int*  bsum  =(int*)   (ws + ((size_t)62<<20));            // 4KB
  float* t    =(float*) (ws + ((size_t)62<<20) + 8192);
  float* ec   =(float*) (ws + ((size_t)62<<20) + 16384);
  float* pmax =(float*) (ws + ((size_t)62<<20) + 57344);    // 8KB
  const float SC = 0.03125f;   // 1/32 per 1-D ortho pass

  // ---- setup
  k_pack<<<HW_/256+1,256,0,stream>>>(xr,xi,Wx0,t,counts,w1,b1,w2,b2,ec);
  k_hist<<<M_/256,256,0,stream>>>(kt,counts,pmax);
  k_scan1<<<1025,256,0,stream>>>(counts,off,bsum,pmax,t);   // +block 1024: pmax -> t[15]
  k_scan2<<<1,256,0,stream>>>(bsum);
  k_reorder12<<<M_/256,256,0,stream>>>(kt,kre,kim,off,bsum,pd,t);
  k_mkWG<<<HW_/1024,256,0,stream>>>(pd,off,bsum,WpH,GyH);

  // ---- full power iteration + op-norm finalization in ONE single-block kernel
  k_power<<<1,256,0,stream>>>(WpH,wraw,t);

  // ---- npcg = 4 PGD iterations
  for (int it=0; it<4; it++){
    float2* xin  = (it&1)? Wx1 : Wx0;
    float2* xout = (it&1)? Wx0 : Wx1;
    float* planar = (it==3)? out : (float*)nullptr;
    k_fft_rows<-1><<<H_,256,0,stream>>>(xin,WF,SC);
    k_fft_cols1<-1><<<H_,256,0,stream>>>(WF,SC);
    k_Tsub_fft<<<H_,256,0,stream>>>(WF,WpH,GyH,G2,SC);
    k_fft_cols1<1><<<H_,256,0,stream>>>(G2,SC);
    k_cnn5<<<1040,256,0,stream>>>(xin,G2,ec,t,xout,planar);
  }
}

// Round 13
// 384.930 us; speedup vs baseline: 2.1272x; 1.0341x over previous
//
#include <hip/hip_runtime.h>
#include <hip/hip_fp16.h>

#define H_  1024
#define W_  1024
#define HW_ (H_*W_)
#define M_  524288

#define SWZ(a) ((a) + ((a)>>4))

// ---------------------------------------------------------------- complex mul
__device__ __forceinline__ float2 cmulf(float2 a, float2 b){
  return make_float2(fmaf(a.x,b.x,-(a.y*b.y)), fmaf(a.x,b.y,a.y*b.x));
}

// ---------------------------------------------------------------- radix-4 bfly
template<int DIR>
__device__ __forceinline__ void bfly4(float2 v[4], int j, int Ns){
  if (Ns>1){
    float ang = ((DIR>0)?6.28318530717958647692f:-6.28318530717958647692f)
                * (float)(j&(Ns-1)) / (float)(4*Ns);
    float s,c; __sincosf(ang,&s,&c);
    float2 w1=make_float2(c,s);
    float2 w2=cmulf(w1,w1);
    float2 w3=cmulf(w2,w1);
    v[1]=cmulf(v[1],w1); v[2]=cmulf(v[2],w2); v[3]=cmulf(v[3],w3);
  }
  float2 t0=make_float2(v[0].x+v[2].x, v[0].y+v[2].y);
  float2 t2=make_float2(v[0].x-v[2].x, v[0].y-v[2].y);
  float2 t1=make_float2(v[1].x+v[3].x, v[1].y+v[3].y);
  float2 t3=make_float2(v[1].x-v[3].x, v[1].y-v[3].y);
  float2 t3r=(DIR<0)?make_float2(t3.y,-t3.x):make_float2(-t3.y,t3.x);
  v[0]=make_float2(t0.x+t1.x,  t0.y+t1.y);
  v[1]=make_float2(t2.x+t3r.x, t2.y+t3r.y);
  v[2]=make_float2(t0.x-t1.x,  t0.y-t1.y);
  v[3]=make_float2(t2.x-t3r.x, t2.y-t3r.y);
}

template<int DIR, int NS>
__device__ __forceinline__ void fft_stage(int j, const float2* src, float2* dst){
  float2 v[4];
#pragma unroll
  for(int r=0;r<4;r++) v[r]=src[SWZ(j+256*r)];
  bfly4<DIR>(v,j,NS);
  int base = ((j & ~(NS-1))<<2) | (j&(NS-1));
#pragma unroll
  for(int r=0;r<4;r++) dst[SWZ(base+NS*r)]=v[r];
}

template<int DIR>
__device__ __forceinline__ void fft1024_core(float2 v[4], int j, float2* A, float2* B, float scale){
  bfly4<DIR>(v,j,1);
#pragma unroll
  for(int r=0;r<4;r++) A[SWZ(4*j+r)]=v[r];
  __syncthreads();
  fft_stage<DIR,4 >(j,A,B); __syncthreads();
  fft_stage<DIR,16>(j,B,A); __syncthreads();
  fft_stage<DIR,64>(j,A,B); __syncthreads();
#pragma unroll
  for(int r=0;r<4;r++) v[r]=B[SWZ(j+256*r)];
  bfly4<DIR>(v,j,256);
#pragma unroll
  for(int r=0;r<4;r++){ v[r].x*=scale; v[r].y*=scale; }
}

// row FFT: fp32 image rows -> fp16 k-space rows (k-space intermediates are
// wreg-suppressed at the output, so fp16 storage is safe -- same argument as
// the verified fp16 weight planes)
template<int DIR>
__global__ __launch_bounds__(256) void k_fft_rows_f2h(const float2* src, __half2* dst, float scale){
  __shared__ float2 A[1088], B[1088];
  int j = threadIdx.x;
  const float2* s = src + (size_t)blockIdx.x*W_;
  float2 v[4];
#pragma unroll
  for(int r=0;r<4;r++) v[r]=s[j+256*r];
  fft1024_core<DIR>(v,j,A,B,scale);
  __half2* d = dst + (size_t)blockIdx.x*W_;
#pragma unroll
  for(int r=0;r<4;r++) d[j+256*r]=__floats2half2_rn(v[r].x,v[r].y);
}

// 1 column per block, in-place on fp16 grid; XCD-aware column swizzle so the
// 16 columns sharing each 64B line live on one XCD's L2.
template<int DIR>
__global__ __launch_bounds__(256) void k_fft_cols1_h(__half2* data, float scale){
  __shared__ float2 A[1088], B[1088];
  int tid=threadIdx.x;
  int col = ((blockIdx.x&7)<<7) + (blockIdx.x>>3);
  float2 v[4];
#pragma unroll
  for(int r=0;r<4;r++) v[r]=__half22float2(data[(size_t)(tid+256*r)*W_ + col]);
  fft1024_core<DIR>(v,tid,A,B,scale);
#pragma unroll
  for(int r=0;r<4;r++) data[(size_t)(tid+256*r)*W_ + col]=__floats2half2_rn(v[r].x,v[r].y);
}

// ---------------------------------------------------------------- init: pack x, zero counts, zero t; block 4096 builds conv tables
// ec layout (floats): [0..99] E[oc*50+ic*25+dy*5+dx]; [100..101] C0;
// [102..119] Bb[oc*9+u]; [120..443] Btab[oc*162+u*18+ic*9+v]; [444..445] b2
__global__ __launch_bounds__(256) void k_pack(const float* xr, const float* xi, float2* X, float* t,
                                              int* counts,
                                              const float* w1, const float* b1,
                                              const float* w2, const float* b2, float* ec){
  __shared__ float sw1[576], sw2[576], sb1[32], sB[324];
  int tid=threadIdx.x;
  if (blockIdx.x==4096){
    for(int p=tid;p<576;p+=256){ sw1[p]=w1[p]; sw2[p]=w2[p]; }
    if(tid<32) sb1[tid]=b1[tid];
    __syncthreads();
    for(int e=tid;e<324;e+=256){
      int oc=e/162, r=e-oc*162, u=r/18, r2=r-u*18, ic=r2/9, v=r2-ic*9;
      float s=0.f;
      for(int cm=0;cm<32;cm++) s=fmaf(sw2[oc*288+cm*9+u], sw1[cm*18+ic*9+v], s);
      sB[e]=s; ec[120+e]=s;
    }
    if(tid<18){
      int oc=tid/9, u=tid-oc*9;
      float s=0.f;
      for(int cm=0;cm<32;cm++) s=fmaf(sw2[oc*288+cm*9+u], sb1[cm], s);
      ec[102+tid]=s;
    }
    if(tid<2){
      float s=b2[tid];
      for(int u=0;u<9;u++){
        float bb=0.f;
        for(int cm=0;cm<32;cm++) bb=fmaf(sw2[tid*288+cm*9+u], sb1[cm], bb);
        s+=bb;
      }
      ec[100+tid]=s;
      ec[444+tid]=b2[tid];
    }
    __syncthreads();
    if(tid<100){
      int oc=tid/50, r=tid-oc*50, ic=r/25, r2=r-ic*25, dy=r2/5, dx=r2-dy*5;
      float s=0.f;
      for(int uy=0;uy<3;uy++){ int vy=dy-uy; if(vy<0||vy>2) continue;
        for(int ux=0;ux<3;ux++){ int vx=dx-ux; if(vx<0||vx>2) continue;
          s+=sB[oc*162+(uy*3+ux)*18+ic*9+vy*3+vx];
        }
      }
      ec[tid]=s;
    }
    return;
  }
  int i = blockIdx.x*256+tid;
  X[i]=make_float2(xr[i],xi[i]);
  counts[i]=0;
  if (blockIdx.x==0 && tid<32) t[tid]=0.f;
}

__global__ __launch_bounds__(256) void k_hist(const float* kt, int* counts, float* pmax){
  int m = blockIdx.x*256+threadIdx.x;
  float r = 0.f;
  {
    float kx=kt[2*m], ky=kt[2*m+1];
    float dx=kx-0.5f, dy=ky-0.5f;
    r = sqrtf(dx*dx+dy*dy);
    int ix = ((int)floorf(kx*1024.f))&1023;
    int iy = ((int)floorf(ky*1024.f))&1023;
    atomicAdd(&counts[(ix<<10)|iy],1);
  }
  for(int o=32;o>0;o>>=1) r = fmaxf(r, __shfl_down(r,o,64));
  __shared__ float sm[4];
  if((threadIdx.x&63)==0) sm[threadIdx.x>>6]=r;
  __syncthreads();
  if(threadIdx.x==0)
    pmax[blockIdx.x] = fmaxf(fmaxf(sm[0],sm[1]),fmaxf(sm[2],sm[3]));
}

// ---------------------------------------------------------------- scan (per-row-local offsets; bsum holds row bases)
// block 1024: fused global max-radius reduction (pmax -> t[15])
__global__ __launch_bounds__(256) void k_scan1(const int* cnt, int* off, int* bsum,
                                               const float* pmax, float* t){
  int tid = threadIdx.x;
  if (blockIdx.x>=1024){
    float s=-1e30f;
    for(int k=tid;k<2048;k+=256) s=fmaxf(s,pmax[k]);
    __shared__ float smx[4];
    for(int o=32;o>0;o>>=1) s=fmaxf(s,__shfl_down(s,o,64));
    if((tid&63)==0) smx[tid>>6]=s;
    __syncthreads();
    if(tid==0) t[15]=fmaxf(fmaxf(smx[0],smx[1]),fmaxf(smx[2],smx[3]));
    return;
  }
  __shared__ int sm[256];
  int base = blockIdx.x*1024;
  int4 c = *(const int4*)(cnt + base + tid*4);
  int s = c.x+c.y+c.z+c.w;
  sm[tid]=s; __syncthreads();
  int v=s;
  for(int o=1;o<256;o<<=1){
    int u = (tid>=o)? sm[tid-o]:0;
    __syncthreads();
    v += u; sm[tid]=v;
    __syncthreads();
  }
  int excl = v - s;
  int4 o4;
  o4.x=excl; o4.y=excl+c.x; o4.z=excl+c.x+c.y; o4.w=excl+c.x+c.y+c.z;
  *(int4*)(off+base+tid*4)=o4;
  if (tid==255) bsum[blockIdx.x]=v;
}

__global__ __launch_bounds__(256) void k_scan2(int* bsum){
  __shared__ int sm[256];
  int tid=threadIdx.x;
  int4 c = *(const int4*)(bsum + tid*4);
  int s = c.x+c.y+c.z+c.w;
  sm[tid]=s; __syncthreads();
  int v=s;
  for(int o=1;o<256;o<<=1){
    int u = (tid>=o)? sm[tid-o]:0;
    __syncthreads();
    v += u; sm[tid]=v;
    __syncthreads();
  }
  int excl=v-s;
  int4 o4;
  o4.x=excl; o4.y=excl+c.x; o4.z=excl+c.x+c.y; o4.w=excl+c.x+c.y+c.z;
  *(int4*)(bsum+tid*4)=o4;
}

// ---------------------------------------------------------------- fused reorder: cell place + dcf + pd write (global pos = local + bsum[row])
// pd[p] = (tx, ty, y_dcf.x, y_dcf.y)  (sorted-by-cell point data)
__global__ __launch_bounds__(256) void k_reorder12(const float* __restrict__ kt,
                                                   const float* __restrict__ kre,
                                                   const float* __restrict__ kim,
                                                   int* __restrict__ off,
                                                   const int* __restrict__ bsum,
                                                   float4* __restrict__ pd,
                                                   const float* __restrict__ t){
  int m = blockIdx.x*256+threadIdx.x;
  float kx=kt[2*m], ky=kt[2*m+1];
  float gx=kx*1024.f, gy=ky*1024.f;
  float fx=floorf(gx), fy=floorf(gy);
  float tx=gx-fx, ty=gy-fy;
  int ix=((int)fx)&1023, iy=((int)fy)&1023;
  int pos = atomicAdd(&off[(ix<<10)|iy],1) + bsum[ix];
  float dx=kx-0.5f, dy=ky-0.5f;
  float r=sqrtf(dx*dx+dy*dy);
  float dcf=sqrtf(r/(t[15]+1e-8f));
  pd[pos]=make_float4(tx,ty,kre[m]*dcf,kim[m]*dcf);
}

// ---------------------------------------------------------------- half-pack helper
__device__ __forceinline__ void store_h4(__half* dst, const float v[4]){
  __half h0=__float2half(v[0]), h1=__float2half(v[1]),
         h2=__float2half(v[2]), h3=__float2half(v[3]);
  short4 s;
  s.x=*(short*)&h0; s.y=*(short*)&h1; s.z=*(short*)&h2; s.w=*(short*)&h3;
  *(short4*)dst=s;
}

// ---------------------------------------------------------------- build T = Grid∘Sample as 5 symmetric stencil planes (fp16)
// + Gy = Grid(y*sqrt_dcf) (fp16) in the same CSR walk. Offsets are row-local + bsum[row].
// Wd[c] = T[c][c+d] = sum_p w_p(c)*w_p(c+d), d in {(0,0),(0,1),(1,0),(1,1),(1,-1)}
__global__ __launch_bounds__(256) void k_mkWG(const float4* __restrict__ pd,
                                              const int* __restrict__ off,
                                              const int* __restrict__ bsum,
                                              __half* __restrict__ WpH,
                                              __half2* __restrict__ GyH){
  int gid=blockIdx.x*256+threadIdx.x;
  int r=gid>>8, c0=(gid&255)<<2;
  float w00[4],wE[4],wS[4],wSE[4],wSW[4],gx[4],gy[4];
#pragma unroll
  for(int q=0;q<4;q++){ w00[q]=0.f;wE[q]=0.f;wS[q]=0.f;wSE[q]=0.f;wSW[q]=0.f;gx[q]=0.f;gy[q]=0.f; }
#pragma unroll
  for(int dr=0;dr<2;dr++){
    int br=(r-dr)&1023;
    int rowbase=br<<10;
    int rb=bsum[br];
    if (c0>0){
      int O[6];
#pragma unroll
      for(int q=0;q<6;q++) O[q]=off[rowbase+c0-2+q]+rb;
#pragma unroll
      for(int i=0;i<5;i++){
        for(int j=O[i]; j<O[i+1]; j++){
          float4 p=pd[j];
          float wx = dr? p.x : 1.f-p.x;
          float uy=1.f-p.y, vy=p.y;
          float a0=wx*uy, a1=wx*vy;          // weights at cols pc, pc+1 (this cell row)
          float wpu=p.x*uy, wpv=p.x*vy;      // partner-row (r+1) weights (valid when dr==0)
          if (i>=1){                          // B=0 cell (col = pc) at slot i-1
            w00[i-1]=fmaf(a0,a0,w00[i-1]);
            wE [i-1]=fmaf(a0,a1,wE [i-1]);
            gx [i-1]=fmaf(a0,p.z,gx[i-1]); gy[i-1]=fmaf(a0,p.w,gy[i-1]);
            if(!dr){ wS[i-1]=fmaf(a0,wpu,wS[i-1]); wSE[i-1]=fmaf(a0,wpv,wSE[i-1]); }
          }
          if (i<=3){                          // B=1 cell (col = pc+1) at slot i
            w00[i]=fmaf(a1,a1,w00[i]);
            gx [i]=fmaf(a1,p.z,gx[i]); gy[i]=fmaf(a1,p.w,gy[i]);
            if(!dr){ wS[i]=fmaf(a1,wpv,wS[i]); wSW[i]=fmaf(a1,wpu,wSW[i]); }
          }
        }
      }
    } else {
      int bw=rowbase+1023;
      int sw=off[bw-1]+rb, ew=off[bw]+rb;
      for(int j=sw;j<ew;j++){                 // wrap: cell col 1023's points, B=1 at slot 0
        float4 p=pd[j];
        float wx = dr? p.x : 1.f-p.x;
        float uy=1.f-p.y, vy=p.y;
        float a1=wx*vy;
        w00[0]=fmaf(a1,a1,w00[0]);
        gx [0]=fmaf(a1,p.z,gx[0]); gy[0]=fmaf(a1,p.w,gy[0]);
        if(!dr){ float wpu=p.x*uy, wpv=p.x*vy;
          wS[0]=fmaf(a1,wpv,wS[0]); wSW[0]=fmaf(a1,wpu,wSW[0]); }
      }
      int O[5];
      O[0]=rb;                                // row start
#pragma unroll
      for(int q=1;q<5;q++) O[q]=off[rowbase+q-1]+rb;
#pragma unroll
      for(int i=0;i<4;i++){
        for(int j=O[i]; j<O[i+1]; j++){
          float4 p=pd[j];
          float wx = dr? p.x : 1.f-p.x;
          float uy=1.f-p.y, vy=p.y;
          float a0=wx*uy, a1=wx*vy;
          float wpu=p.x*uy, wpv=p.x*vy;
          w00[i]=fmaf(a0,a0,w00[i]);
          wE [i]=fmaf(a0,a1,wE [i]);
          gx [i]=fmaf(a0,p.z,gx[i]); gy[i]=fmaf(a0,p.w,gy[i]);
          if(!dr){ wS[i]=fmaf(a0,wpu,wS[i]); wSE[i]=fmaf(a0,wpv,wSE[i]); }
          if (i<=2){
            w00[i+1]=fmaf(a1,a1,w00[i+1]);
            gx [i+1]=fmaf(a1,p.z,gx[i+1]); gy[i+1]=fmaf(a1,p.w,gy[i+1]);
            if(!dr){ wS[i+1]=fmaf(a1,wpv,wS[i+1]); wSW[i+1]=fmaf(a1,wpu,wSW[i+1]); }
          }
        }
      }
    }
  }
  size_t base=((size_t)r<<10)+c0;
  store_h4(&WpH[base],               w00);
  store_h4(&WpH[(size_t)HW_+base],   wE );
  store_h4(&WpH[(size_t)2*HW_+base], wS );
  store_h4(&WpH[(size_t)3*HW_+base], wSE);
  store_h4(&WpH[(size_t)4*HW_+base], wSW);
#pragma unroll
  for(int q=0;q<4;q++) GyH[base+q]=__floats2half2_rn(gx[q],gy[q]);
}

// ---------------------------------------------------------------- 9-tap symmetric stencil, complex field (fp16 weights)
__device__ __forceinline__ float2 t_tap(const float2* __restrict__ Fm, const float2* __restrict__ F0,
                                        const float2* __restrict__ Fp, const __half* __restrict__ WpH,
                                        int rowW, int rowWm, int c){
  int cm=(c+1023)&1023, cp=(c+1)&1023;
  const __half* W00=WpH;
  const __half* WE =WpH+(size_t)HW_;
  const __half* WS =WpH+(size_t)2*HW_;
  const __half* WSE=WpH+(size_t)3*HW_;
  const __half* WSW=WpH+(size_t)4*HW_;
  float2 f=F0[c];
  float w=__half2float(W00[rowW+c]);
  float ux=w*f.x, uy=w*f.y;
  f=F0[cp]; w=__half2float(WE [rowW +c ]); ux=fmaf(w,f.x,ux); uy=fmaf(w,f.y,uy);  // +E
  f=F0[cm]; w=__half2float(WE [rowW +cm]); ux=fmaf(w,f.x,ux); uy=fmaf(w,f.y,uy);  // -E
  f=Fp[c ]; w=__half2float(WS [rowW +c ]); ux=fmaf(w,f.x,ux); uy=fmaf(w,f.y,uy);  // +S
  f=Fm[c ]; w=__half2float(WS [rowWm+c ]); ux=fmaf(w,f.x,ux); uy=fmaf(w,f.y,uy);  // -S
  f=Fp[cp]; w=__half2float(WSE[rowW +c ]); ux=fmaf(w,f.x,ux); uy=fmaf(w,f.y,uy);  // +SE
  f=Fm[cm]; w=__half2float(WSE[rowWm+cm]); ux=fmaf(w,f.x,ux); uy=fmaf(w,f.y,uy);  // -SE
  f=Fp[cm]; w=__half2float(WSW[rowW +c ]); ux=fmaf(w,f.x,ux); uy=fmaf(w,f.y,uy);  // +SW
  f=Fm[cp]; w=__half2float(WSW[rowWm+cp]); ux=fmaf(w,f.x,ux); uy=fmaf(w,f.y,uy);  // -SW
  return make_float2(ux,uy);
}

// ---------------------------------------------------------------- single-block power iteration on the 21x21 support
// S_1 = 1024*T(:,DC) has 9 nonzeros; T couples +-1 cell/application, so after
// 10 applications the support is <= +-10. The full power chain (init + 9
// normalized sweeps + op-norm finalization) runs in one block on a 25x25
// wrapped patch. Arithmetic per nonzero cell is identical to the full-grid
// version (same fmaf tap order, same fp16 weights, same eps chain).
__global__ __launch_bounds__(256) void k_power(const __half* __restrict__ WpH,
                                               const float* __restrict__ wraw,
                                               float* __restrict__ t){
  __shared__ float Wp5[5][25][25];   // wrapped weight window, offsets -12..+12
  __shared__ float Fa[25][25], Fb[25][25];
  __shared__ float red[8];
  int tid=threadIdx.x;
  // stage weights (grid coord = (patch+1012)&1023)
  for(int idx=tid; idx<3125; idx+=256){
    int d=idx/625, rem=idx-d*625, pr=rem/25, pc=rem-(rem/25)*25;
    int gr=(pr+1012)&1023, gc=(pc+1012)&1023;
    Wp5[d][pr][pc]=__half2float(WpH[(size_t)d*HW_+((size_t)gr<<10)+gc]);
  }
  for(int idx=tid; idx<625; idx+=256){
    int pr=idx/25, pc=idx-(idx/25)*25;
    Fa[pr][pc]=0.f; Fb[pr][pc]=0.f;
  }
  __syncthreads();
  // init: S_1 = 1024*T(:,DC)  (9 entries around center 12,12)
  if (tid==0){
    float bb=0.f, v;
    v=1024.f*Wp5[0][12][12]; Fa[12][12]=v; bb=fmaf(v,v,bb);   // ( 0, 0)
    v=1024.f*Wp5[1][12][12]; Fa[12][13]=v; bb=fmaf(v,v,bb);   // ( 0, 1)
    v=1024.f*Wp5[1][12][11]; Fa[12][11]=v; bb=fmaf(v,v,bb);   // ( 0,-1)
    v=1024.f*Wp5[2][12][12]; Fa[13][12]=v; bb=fmaf(v,v,bb);   // ( 1, 0)
    v=1024.f*Wp5[3][12][12]; Fa[13][13]=v; bb=fmaf(v,v,bb);   // ( 1, 1)
    v=1024.f*Wp5[4][12][12]; Fa[13][11]=v; bb=fmaf(v,v,bb);   // ( 1,-1)
    v=1024.f*Wp5[2][11][12]; Fa[11][12]=v; bb=fmaf(v,v,bb);   // (-1, 0)
    v=1024.f*Wp5[4][11][13]; Fa[11][13]=v; bb=fmaf(v,v,bb);   // (-1, 1)
    v=1024.f*Wp5[3][11][11]; Fa[11][11]=v; bb=fmaf(v,v,bb);   // (-1,-1)
    red[0]=bb;
  }
  __syncthreads();
  float b=red[0];
  float (*cur)[25]=Fa, (*nxt)[25]=Fb;
  int lane=tid&63, wid=tid>>6;
  for(int n=0;n<9;n++){
    float sc=1.f/(sqrtf(b)+1e-12f);
    float dot=0.f, nsq=0.f;
    for(int idx=tid; idx<441; idx+=256){
      int pr=2+idx/21, pc=2+(idx-(idx/21)*21);
      float u = Wp5[0][pr][pc]*cur[pr][pc];
      u=fmaf(Wp5[1][pr][pc  ],cur[pr  ][pc+1],u);
      u=fmaf(Wp5[1][pr][pc-1],cur[pr  ][pc-1],u);
      u=fmaf(Wp5[2][pr][pc  ],cur[pr+1][pc  ],u);
      u=fmaf(Wp5[2][pr-1][pc],cur[pr-1][pc  ],u);
      u=fmaf(Wp5[3][pr][pc  ],cur[pr+1][pc+1],u);
      u=fmaf(Wp5[3][pr-1][pc-1],cur[pr-1][pc-1],u);
      u=fmaf(Wp5[4][pr][pc  ],cur[pr+1][pc-1],u);
      u=fmaf(Wp5[4][pr-1][pc+1],cur[pr-1][pc+1],u);
      dot=fmaf(cur[pr][pc],u,dot);
      float o=u*sc;
      nsq=fmaf(o,o,nsq);
      nxt[pr][pc]=o;
    }
    for(int o=32;o>0;o>>=1){ dot+=__shfl_down(dot,o,64); nsq+=__shfl_down(nsq,o,64); }
    __syncthreads();                 // tap reads + prior red reads complete
    if(lane==0){ red[wid]=nsq; red[4+wid]=dot; }
    __syncthreads();
    if(tid==0){
      float nsum=red[0]+red[1]+red[2]+red[3];
      float dsum=red[4]+red[5]+red[6]+red[7];
      if (n==8){
        float a=sc*sc*dsum;          // ||av_10||^2
        float vn=sqrtf(b)*sc;        // ||v_9||
        float opn=sqrtf(a)/(vn+1e-12f);
        float sig=1.f/(1.f+__expf(-wraw[0]));
        t[19]=2.f*sig/(opn*opn);
      }
      red[0]=nsum;
    }
    __syncthreads();
    b=red[0];
    float (*tmp)[25]=cur; cur=nxt; nxt=tmp;
  }
}

// ---------------------------------------------------------------- npcg: G2_row = rowIFFT( T*F - Gy ), block = k-grid row (fp16 I/O)
__global__ __launch_bounds__(256) void k_Tsub_fft(const __half2* __restrict__ Fin,
    const __half* __restrict__ WpH, const __half2* __restrict__ GyH,
    __half2* __restrict__ G2, float scale){
  __shared__ __align__(16) float2 Fsm[3][1024];   // reused as FFT scratch A|B after taps
  int r=blockIdx.x, tid=threadIdx.x;
  int rm=(r+1023)&1023, rp=(r+1)&1023;
  {
    const __half2* s0=Fin+((size_t)rm<<10);
    const __half2* s1=Fin+((size_t)r <<10);
    const __half2* s2=Fin+((size_t)rp<<10);
    for(int p2=tid;p2<1024;p2+=256){
      Fsm[0][p2]=__half22float2(s0[p2]);
      Fsm[1][p2]=__half22float2(s1[p2]);
      Fsm[2][p2]=__half22float2(s2[p2]);
    }
  }
  __syncthreads();
  int rowW=r<<10, rowWm=rm<<10;
  float2 v[4];
  const __half2* gyr=GyH+((size_t)r<<10);
#pragma unroll
  for(int q=0;q<4;q++){
    int c=tid+256*q;
    float2 u=t_tap(&Fsm[0][0],&Fsm[1][0],&Fsm[2][0],WpH,rowW,rowWm,c);
    float2 gy=__half22float2(gyr[c]);
    v[q]=make_float2(u.x-gy.x,u.y-gy.y);   // note: c = tid+256q IS the fft1024_core input layout
  }
  __syncthreads();                          // all Fsm reads done before aliasing
  float2* A=(float2*)Fsm; float2* B=A+1088;
  fft1024_core<1>(v,tid,A,B,scale);
  __half2* d=G2+((size_t)r<<10);
#pragma unroll
  for(int rr=0;rr<4;rr++) d[tid+256*rr]=__floats2half2_rn(v[rr].x,v[rr].y);
}

// ---------------------------------------------------------------- fused 5x5 composed CNN + update (res in fp16)
// blocks 0..1023: interior tiles (skip border pixels); blocks 1024..1039: border ring
#define CT_S 41
__global__ __launch_bounds__(256) void k_cnn5(const float2* __restrict__ x, const __half2* __restrict__ res,
    const float* __restrict__ ec, const float* __restrict__ t,
    float2* __restrict__ xout, float* __restrict__ outPlanar){
  int tid=threadIdx.x;
  if (blockIdx.x>=1024){
    // ---- border ring: exact conv2(conv1) with h zero-masked outside image
    int id = (blockIdx.x-1024)*256+tid;   // 4096
    int py,px;
    if (id<1024){ py=0; px=id; }
    else if(id<2048){ py=1023; px=id-1024; }
    else if(id<3072){ py=id-2048; px=0; }
    else { py=id-3072; px=1023; }
    float s0=ec[444], s1=ec[445];
    for(int uy=0;uy<3;uy++){
      int qy=py+uy-1; if((unsigned)qy>=1024u) continue;
      for(int ux=0;ux<3;ux++){
        int qx=px+ux-1; if((unsigned)qx>=1024u) continue;
        int u=uy*3+ux;
        s0+=ec[102+u]; s1+=ec[111+u];
        const float* B0=&ec[120+u*18];
        const float* B1=&ec[282+u*18];
        for(int vy=0;vy<3;vy++){
          int sy2=qy+vy-1; if((unsigned)sy2>=1024u) continue;
          for(int vx=0;vx<3;vx++){
            int sx2=qx+vx-1; if((unsigned)sx2>=1024u) continue;
            int v=vy*3+vx;
            float2 xv=x[(size_t)sy2*W_+sx2];
            s0 = fmaf(B0[v],xv.x,fmaf(B0[9+v],xv.y,s0));
            s1 = fmaf(B1[v],xv.x,fmaf(B1[9+v],xv.y,s1));
          }
        }
      }
    }
    float wreg=t[19];
    size_t base=(size_t)py*W_+px;
    float2 xv=x[base];
    float2 rv=__half22float2(res[base]);
    float o0=xv.x - wreg*rv.x - s0;
    float o1=xv.y - wreg*rv.y - s1;
    if (outPlanar){ outPlanar[base]=o0; outPlanar[HW_+base]=o1; }
    else          { xout[base]=make_float2(o0,o1); }
    return;
  }
  __shared__ float xt0[36*CT_S];
  __shared__ float xt1[36*CT_S];
  __shared__ float sE[102];
  int by=blockIdx.x>>5, bx=blockIdx.x&31;
  int ty0=by<<5, tx0=bx<<5;
  for(int p=tid;p<102;p+=256) sE[p]=ec[p];
  for(int p=tid;p<1296;p+=256){
    int r=p/36, c=p-r*36;
    int gy=ty0-2+r, gx=tx0-2+c;
    float vx=0.f, vy=0.f;
    if((unsigned)gy<1024u && (unsigned)gx<1024u){ float2 v=x[(size_t)gy*W_+gx]; vx=v.x; vy=v.y; }
    xt0[r*CT_S+c]=vx; xt1[r*CT_S+c]=vy;
  }
  __syncthreads();
  int row=tid>>3, c4=(tid&7)<<2;
  float a0[4], a1[4];
  float C00=sE[100], C01=sE[101];
#pragma unroll
  for(int jj=0;jj<4;jj++){ a0[jj]=C00; a1[jj]=C01; }
#pragma unroll
  for(int dy=0;dy<5;dy++){
    const float* r0=&xt0[(row+dy)*CT_S+c4];
    const float* r1=&xt1[(row+dy)*CT_S+c4];
    float f0[9], f1[9];
#pragma unroll
    for(int q=0;q<9;q++){ f0[q]=r0[q]; f1[q]=r1[q]; }
#pragma unroll
    for(int dx=0;dx<5;dx++){
      float e00=sE[dy*5+dx], e01=sE[25+dy*5+dx];
      float e10=sE[50+dy*5+dx], e11=sE[75+dy*5+dx];
#pragma unroll
      for(int jj=0;jj<4;jj++){
        a0[jj]=fmaf(e00,f0[jj+dx],fmaf(e01,f1[jj+dx],a0[jj]));
        a1[jj]=fmaf(e10,f0[jj+dx],fmaf(e11,f1[jj+dx],a1[jj]));
      }
    }
  }
  int py=ty0+row;
  float wreg = t[19];
  size_t base=(size_t)py*W_ + tx0 + c4;
  bool rowEdge = (py==0)||(py==1023);
  if (outPlanar){
#pragma unroll
    for(int jj=0;jj<4;jj++){
      int px=tx0+c4+jj;
      if (rowEdge || px==0 || px==1023) continue;   // ring blocks own these
      float2 rv=__half22float2(res[base+jj]);
      float xr_=xt0[(row+2)*CT_S+c4+jj+2];
      float xi_=xt1[(row+2)*CT_S+c4+jj+2];
      outPlanar[base+jj]      = xr_ - wreg*rv.x - a0[jj];
      outPlanar[HW_+base+jj]  = xi_ - wreg*rv.y - a1[jj];
    }
  } else {
#pragma unroll
    for(int jj=0;jj<4;jj++){
      int px=tx0+c4+jj;
      if (rowEdge || px==0 || px==1023) continue;
      float2 rv=__half22float2(res[base+jj]);
      float xr_=xt0[(row+2)*CT_S+c4+jj+2];
      float xi_=xt1[(row+2)*CT_S+c4+jj+2];
      xout[base+jj]=make_float2(xr_ - wreg*rv.x - a0[jj],
                                xi_ - wreg*rv.y - a1[jj]);
    }
  }
}

// ================================================================ launch
extern "C" void kernel_launch(void* const* d_in, const int* in_sizes, int n_in,
                              void* d_out, int out_size, void* d_ws, size_t ws_size,
                              hipStream_t stream){
  (void)in_sizes; (void)n_in; (void)out_size; (void)ws_size;
  const float* xr  =(const float*)d_in[0];
  const float* xi  =(const float*)d_in[1];
  const float* kre =(const float*)d_in[2];
  const float* kim =(const float*)d_in[3];
  const float* kt  =(const float*)d_in[4];
  const float* wraw=(const float*)d_in[5];
  const float* w1  =(const float*)d_in[6];
  const float* b1  =(const float*)d_in[7];
  const float* w2  =(const float*)d_in[8];
  const float* b2  =(const float*)d_in[9];
  float* out = (float*)d_out;

  char* ws=(char*)d_ws;
  float2* Wx0 =(float2*)(ws);                      // 8MB
  float2* Wx1 =(float2*)(ws + ((size_t) 8<<20));   // 8MB
  int*   counts=(int*)  (ws + ((size_t) 8<<20));   // 4MB alias of Wx1 (setup only)
  __half2* WF =(__half2*)(ws + ((size_t)16<<20));  // 4MB  fwd-FFT k-grid (fp16)
  float4* pd  =(float4*)(ws + ((size_t)24<<20));   // 8MB  (tx,ty,ydcf.x,ydcf.y) sorted
  __half2* G2 =(__half2*)(ws + ((size_t)32<<20));  // 4MB  npcg residual grid (fp16)
  int*  off   =(int*)   (ws + ((size_t)40<<20));   // 4MB  CSR ends (row-local)
  __half2* GyH=(__half2*)(ws + ((size_t)44<<20));  // 4MB  Grid(y*sqrt_dcf) fp16
  __half* WpH =(__half*)(ws + ((size_t)52<<20));   // 10MB 5 stencil planes (fp16)
  int*  bsum  =(int*)   (ws + ((size_t)62<<20));            // 4KB
  float* t    =(float*) (ws + ((size_t)62<<20) + 8192);
  float* ec   =(float*) (ws + ((size_t)62<<20) + 16384);
  float* pmax =(float*) (ws + ((size_t)62<<20) + 57344);    // 8KB
  const float SC = 0.03125f;   // 1/32 per 1-D ortho pass

  // ---- setup
  k_pack<<<HW_/256+1,256,0,stream>>>(xr,xi,Wx0,t,counts,w1,b1,w2,b2,ec);
  k_hist<<<M_/256,256,0,stream>>>(kt,counts,pmax);
  k_scan1<<<1025,256,0,stream>>>(counts,off,bsum,pmax,t);   // +block 1024: pmax -> t[15]
  k_scan2<<<1,256,0,stream>>>(bsum);
  k_reorder12<<<M_/256,256,0,stream>>>(kt,kre,kim,off,bsum,pd,t);
  k_mkWG<<<HW_/1024,256,0,stream>>>(pd,off,bsum,WpH,GyH);

  // ---- full power iteration + op-norm finalization in ONE single-block kernel
  k_power<<<1,256,0,stream>>>(WpH,wraw,t);

  // ---- npcg = 4 PGD iterations (k-space intermediates in fp16)
  for (int it=0; it<4; it++){
    float2* xin  = (it&1)? Wx1 : Wx0;
    float2* xout = (it&1)? Wx0 : Wx1;
    float* planar = (it==3)? out : (float*)nullptr;
    k_fft_rows_f2h<-1><<<H_,256,0,stream>>>(xin,WF,SC);
    k_fft_cols1_h<-1><<<H_,256,0,stream>>>(WF,SC);
    k_Tsub_fft<<<H_,256,0,stream>>>(WF,WpH,GyH,G2,SC);
    k_fft_cols1_h<1><<<H_,256,0,stream>>>(G2,SC);
    k_cnn5<<<1040,256,0,stream>>>(xin,G2,ec,t,xout,planar);
  }
}

// Round 14
// 382.087 us; speedup vs baseline: 2.1430x; 1.0074x over previous
//
#include <hip/hip_runtime.h>
#include <hip/hip_fp16.h>

#define H_  1024
#define W_  1024
#define HW_ (H_*W_)
#define M_  524288
#define LDW_ 1040   // padded leading dim (in __half2) for k-space grids: 4160B row
                    // stride breaks the 4KB power-of-2 column stride that aliases
                    // L2/HBM channels on the column-FFT walk

#define SWZ(a) ((a) + ((a)>>4))

// ---------------------------------------------------------------- complex mul
__device__ __forceinline__ float2 cmulf(float2 a, float2 b){
  return make_float2(fmaf(a.x,b.x,-(a.y*b.y)), fmaf(a.x,b.y,a.y*b.x));
}

// ---------------------------------------------------------------- radix-4 bfly
template<int DIR>
__device__ __forceinline__ void bfly4(float2 v[4], int j, int Ns){
  if (Ns>1){
    float ang = ((DIR>0)?6.28318530717958647692f:-6.28318530717958647692f)
                * (float)(j&(Ns-1)) / (float)(4*Ns);
    float s,c; __sincosf(ang,&s,&c);
    float2 w1=make_float2(c,s);
    float2 w2=cmulf(w1,w1);
    float2 w3=cmulf(w2,w1);
    v[1]=cmulf(v[1],w1); v[2]=cmulf(v[2],w2); v[3]=cmulf(v[3],w3);
  }
  float2 t0=make_float2(v[0].x+v[2].x, v[0].y+v[2].y);
  float2 t2=make_float2(v[0].x-v[2].x, v[0].y-v[2].y);
  float2 t1=make_float2(v[1].x+v[3].x, v[1].y+v[3].y);
  float2 t3=make_float2(v[1].x-v[3].x, v[1].y-v[3].y);
  float2 t3r=(DIR<0)?make_float2(t3.y,-t3.x):make_float2(-t3.y,t3.x);
  v[0]=make_float2(t0.x+t1.x,  t0.y+t1.y);
  v[1]=make_float2(t2.x+t3r.x, t2.y+t3r.y);
  v[2]=make_float2(t0.x-t1.x,  t0.y-t1.y);
  v[3]=make_float2(t2.x-t3r.x, t2.y-t3r.y);
}

template<int DIR, int NS>
__device__ __forceinline__ void fft_stage(int j, const float2* src, float2* dst){
  float2 v[4];
#pragma unroll
  for(int r=0;r<4;r++) v[r]=src[SWZ(j+256*r)];
  bfly4<DIR>(v,j,NS);
  int base = ((j & ~(NS-1))<<2) | (j&(NS-1));
#pragma unroll
  for(int r=0;r<4;r++) dst[SWZ(base+NS*r)]=v[r];
}

template<int DIR>
__device__ __forceinline__ void fft1024_core(float2 v[4], int j, float2* A, float2* B, float scale){
  bfly4<DIR>(v,j,1);
#pragma unroll
  for(int r=0;r<4;r++) A[SWZ(4*j+r)]=v[r];
  __syncthreads();
  fft_stage<DIR,4 >(j,A,B); __syncthreads();
  fft_stage<DIR,16>(j,B,A); __syncthreads();
  fft_stage<DIR,64>(j,A,B); __syncthreads();
#pragma unroll
  for(int r=0;r<4;r++) v[r]=B[SWZ(j+256*r)];
  bfly4<DIR>(v,j,256);
#pragma unroll
  for(int r=0;r<4;r++){ v[r].x*=scale; v[r].y*=scale; }
}

// row FFT: fp32 image rows -> fp16 k-space rows (padded LDW_)
template<int DIR>
__global__ __launch_bounds__(256) void k_fft_rows_f2h(const float2* src, __half2* dst, float scale){
  __shared__ float2 A[1088], B[1088];
  int j = threadIdx.x;
  const float2* s = src + (size_t)blockIdx.x*W_;
  float2 v[4];
#pragma unroll
  for(int r=0;r<4;r++) v[r]=s[j+256*r];
  fft1024_core<DIR>(v,j,A,B,scale);
  __half2* d = dst + (size_t)blockIdx.x*LDW_;
#pragma unroll
  for(int r=0;r<4;r++) d[j+256*r]=__floats2half2_rn(v[r].x,v[r].y);
}

// 1 column per block, in-place on padded fp16 grid; XCD-aware column swizzle.
template<int DIR>
__global__ __launch_bounds__(256) void k_fft_cols1_h(__half2* data, float scale){
  __shared__ float2 A[1088], B[1088];
  int tid=threadIdx.x;
  int col = ((blockIdx.x&7)<<7) + (blockIdx.x>>3);
  float2 v[4];
#pragma unroll
  for(int r=0;r<4;r++) v[r]=__half22float2(data[(size_t)(tid+256*r)*LDW_ + col]);
  fft1024_core<DIR>(v,tid,A,B,scale);
#pragma unroll
  for(int r=0;r<4;r++) data[(size_t)(tid+256*r)*LDW_ + col]=__floats2half2_rn(v[r].x,v[r].y);
}

// ---------------------------------------------------------------- init: pack x, zero counts, zero t; block 4096 builds conv tables
// ec layout (floats): [0..99] E[oc*50+ic*25+dy*5+dx]; [100..101] C0;
// [102..119] Bb[oc*9+u]; [120..443] Btab[oc*162+u*18+ic*9+v]; [444..445] b2
__global__ __launch_bounds__(256) void k_pack(const float* xr, const float* xi, float2* X, float* t,
                                              int* counts,
                                              const float* w1, const float* b1,
                                              const float* w2, const float* b2, float* ec){
  __shared__ float sw1[576], sw2[576], sb1[32], sB[324];
  int tid=threadIdx.x;
  if (blockIdx.x==4096){
    for(int p=tid;p<576;p+=256){ sw1[p]=w1[p]; sw2[p]=w2[p]; }
    if(tid<32) sb1[tid]=b1[tid];
    __syncthreads();
    for(int e=tid;e<324;e+=256){
      int oc=e/162, r=e-oc*162, u=r/18, r2=r-u*18, ic=r2/9, v=r2-ic*9;
      float s=0.f;
      for(int cm=0;cm<32;cm++) s=fmaf(sw2[oc*288+cm*9+u], sw1[cm*18+ic*9+v], s);
      sB[e]=s; ec[120+e]=s;
    }
    if(tid<18){
      int oc=tid/9, u=tid-oc*9;
      float s=0.f;
      for(int cm=0;cm<32;cm++) s=fmaf(sw2[oc*288+cm*9+u], sb1[cm], s);
      ec[102+tid]=s;
    }
    if(tid<2){
      float s=b2[tid];
      for(int u=0;u<9;u++){
        float bb=0.f;
        for(int cm=0;cm<32;cm++) bb=fmaf(sw2[tid*288+cm*9+u], sb1[cm], bb);
        s+=bb;
      }
      ec[100+tid]=s;
      ec[444+tid]=b2[tid];
    }
    __syncthreads();
    if(tid<100){
      int oc=tid/50, r=tid-oc*50, ic=r/25, r2=r-ic*25, dy=r2/5, dx=r2-dy*5;
      float s=0.f;
      for(int uy=0;uy<3;uy++){ int vy=dy-uy; if(vy<0||vy>2) continue;
        for(int ux=0;ux<3;ux++){ int vx=dx-ux; if(vx<0||vx>2) continue;
          s+=sB[oc*162+(uy*3+ux)*18+ic*9+vy*3+vx];
        }
      }
      ec[tid]=s;
    }
    return;
  }
  int i = blockIdx.x*256+tid;
  X[i]=make_float2(xr[i],xi[i]);
  counts[i]=0;
  if (blockIdx.x==0 && tid<32) t[tid]=0.f;
}

__global__ __launch_bounds__(256) void k_hist(const float* kt, int* counts, float* pmax){
  int m = blockIdx.x*256+threadIdx.x;
  float r = 0.f;
  {
    float kx=kt[2*m], ky=kt[2*m+1];
    float dx=kx-0.5f, dy=ky-0.5f;
    r = sqrtf(dx*dx+dy*dy);
    int ix = ((int)floorf(kx*1024.f))&1023;
    int iy = ((int)floorf(ky*1024.f))&1023;
    atomicAdd(&counts[(ix<<10)|iy],1);
  }
  for(int o=32;o>0;o>>=1) r = fmaxf(r, __shfl_down(r,o,64));
  __shared__ float sm[4];
  if((threadIdx.x&63)==0) sm[threadIdx.x>>6]=r;
  __syncthreads();
  if(threadIdx.x==0)
    pmax[blockIdx.x] = fmaxf(fmaxf(sm[0],sm[1]),fmaxf(sm[2],sm[3]));
}

// ---------------------------------------------------------------- scan (per-row-local offsets; bsum holds row bases)
// block 1024: fused global max-radius reduction (pmax -> t[15])
__global__ __launch_bounds__(256) void k_scan1(const int* cnt, int* off, int* bsum,
                                               const float* pmax, float* t){
  int tid = threadIdx.x;
  if (blockIdx.x>=1024){
    float s=-1e30f;
    for(int k=tid;k<2048;k+=256) s=fmaxf(s,pmax[k]);
    __shared__ float smx[4];
    for(int o=32;o>0;o>>=1) s=fmaxf(s,__shfl_down(s,o,64));
    if((tid&63)==0) smx[tid>>6]=s;
    __syncthreads();
    if(tid==0) t[15]=fmaxf(fmaxf(smx[0],smx[1]),fmaxf(smx[2],smx[3]));
    return;
  }
  __shared__ int sm[256];
  int base = blockIdx.x*1024;
  int4 c = *(const int4*)(cnt + base + tid*4);
  int s = c.x+c.y+c.z+c.w;
  sm[tid]=s; __syncthreads();
  int v=s;
  for(int o=1;o<256;o<<=1){
    int u = (tid>=o)? sm[tid-o]:0;
    __syncthreads();
    v += u; sm[tid]=v;
    __syncthreads();
  }
  int excl = v - s;
  int4 o4;
  o4.x=excl; o4.y=excl+c.x; o4.z=excl+c.x+c.y; o4.w=excl+c.x+c.y+c.z;
  *(int4*)(off+base+tid*4)=o4;
  if (tid==255) bsum[blockIdx.x]=v;
}

__global__ __launch_bounds__(256) void k_scan2(int* bsum){
  __shared__ int sm[256];
  int tid=threadIdx.x;
  int4 c = *(const int4*)(bsum + tid*4);
  int s = c.x+c.y+c.z+c.w;
  sm[tid]=s; __syncthreads();
  int v=s;
  for(int o=1;o<256;o<<=1){
    int u = (tid>=o)? sm[tid-o]:0;
    __syncthreads();
    v += u; sm[tid]=v;
    __syncthreads();
  }
  int excl=v-s;
  int4 o4;
  o4.x=excl; o4.y=excl+c.x; o4.z=excl+c.x+c.y; o4.w=excl+c.x+c.y+c.z;
  *(int4*)(bsum+tid*4)=o4;
}

// ---------------------------------------------------------------- fused reorder: cell place + dcf + pd write (global pos = local + bsum[row])
// pd[p] = (tx, ty, y_dcf.x, y_dcf.y)  (sorted-by-cell point data)
__global__ __launch_bounds__(256) void k_reorder12(const float* __restrict__ kt,
                                                   const float* __restrict__ kre,
                                                   const float* __restrict__ kim,
                                                   int* __restrict__ off,
                                                   const int* __restrict__ bsum,
                                                   float4* __restrict__ pd,
                                                   const float* __restrict__ t){
  int m = blockIdx.x*256+threadIdx.x;
  float kx=kt[2*m], ky=kt[2*m+1];
  float gx=kx*1024.f, gy=ky*1024.f;
  float fx=floorf(gx), fy=floorf(gy);
  float tx=gx-fx, ty=gy-fy;
  int ix=((int)fx)&1023, iy=((int)fy)&1023;
  int pos = atomicAdd(&off[(ix<<10)|iy],1) + bsum[ix];
  float dx=kx-0.5f, dy=ky-0.5f;
  float r=sqrtf(dx*dx+dy*dy);
  float dcf=sqrtf(r/(t[15]+1e-8f));
  pd[pos]=make_float4(tx,ty,kre[m]*dcf,kim[m]*dcf);
}

// ---------------------------------------------------------------- half-pack helper
__device__ __forceinline__ void store_h4(__half* dst, const float v[4]){
  __half h0=__float2half(v[0]), h1=__float2half(v[1]),
         h2=__float2half(v[2]), h3=__float2half(v[3]);
  short4 s;
  s.x=*(short*)&h0; s.y=*(short*)&h1; s.z=*(short*)&h2; s.w=*(short*)&h3;
  *(short4*)dst=s;
}

// ---------------------------------------------------------------- build T = Grid∘Sample as 5 symmetric stencil planes (fp16)
// + Gy = Grid(y*sqrt_dcf) (fp16) in the same CSR walk. Offsets are row-local + bsum[row].
// Wd[c] = T[c][c+d] = sum_p w_p(c)*w_p(c+d), d in {(0,0),(0,1),(1,0),(1,1),(1,-1)}
__global__ __launch_bounds__(256) void k_mkWG(const float4* __restrict__ pd,
                                              const int* __restrict__ off,
                                              const int* __restrict__ bsum,
                                              __half* __restrict__ WpH,
                                              __half2* __restrict__ GyH){
  int gid=blockIdx.x*256+threadIdx.x;
  int r=gid>>8, c0=(gid&255)<<2;
  float w00[4],wE[4],wS[4],wSE[4],wSW[4],gx[4],gy[4];
#pragma unroll
  for(int q=0;q<4;q++){ w00[q]=0.f;wE[q]=0.f;wS[q]=0.f;wSE[q]=0.f;wSW[q]=0.f;gx[q]=0.f;gy[q]=0.f; }
#pragma unroll
  for(int dr=0;dr<2;dr++){
    int br=(r-dr)&1023;
    int rowbase=br<<10;
    int rb=bsum[br];
    if (c0>0){
      int O[6];
#pragma unroll
      for(int q=0;q<6;q++) O[q]=off[rowbase+c0-2+q]+rb;
#pragma unroll
      for(int i=0;i<5;i++){
        for(int j=O[i]; j<O[i+1]; j++){
          float4 p=pd[j];
          float wx = dr? p.x : 1.f-p.x;
          float uy=1.f-p.y, vy=p.y;
          float a0=wx*uy, a1=wx*vy;          // weights at cols pc, pc+1 (this cell row)
          float wpu=p.x*uy, wpv=p.x*vy;      // partner-row (r+1) weights (valid when dr==0)
          if (i>=1){                          // B=0 cell (col = pc) at slot i-1
            w00[i-1]=fmaf(a0,a0,w00[i-1]);
            wE [i-1]=fmaf(a0,a1,wE [i-1]);
            gx [i-1]=fmaf(a0,p.z,gx[i-1]); gy[i-1]=fmaf(a0,p.w,gy[i-1]);
            if(!dr){ wS[i-1]=fmaf(a0,wpu,wS[i-1]); wSE[i-1]=fmaf(a0,wpv,wSE[i-1]); }
          }
          if (i<=3){                          // B=1 cell (col = pc+1) at slot i
            w00[i]=fmaf(a1,a1,w00[i]);
            gx [i]=fmaf(a1,p.z,gx[i]); gy[i]=fmaf(a1,p.w,gy[i]);
            if(!dr){ wS[i]=fmaf(a1,wpv,wS[i]); wSW[i]=fmaf(a1,wpu,wSW[i]); }
          }
        }
      }
    } else {
      int bw=rowbase+1023;
      int sw=off[bw-1]+rb, ew=off[bw]+rb;
      for(int j=sw;j<ew;j++){                 // wrap: cell col 1023's points, B=1 at slot 0
        float4 p=pd[j];
        float wx = dr? p.x : 1.f-p.x;
        float uy=1.f-p.y, vy=p.y;
        float a1=wx*vy;
        w00[0]=fmaf(a1,a1,w00[0]);
        gx [0]=fmaf(a1,p.z,gx[0]); gy[0]=fmaf(a1,p.w,gy[0]);
        if(!dr){ float wpu=p.x*uy, wpv=p.x*vy;
          wS[0]=fmaf(a1,wpv,wS[0]); wSW[0]=fmaf(a1,wpu,wSW[0]); }
      }
      int O[5];
      O[0]=rb;                                // row start
#pragma unroll
      for(int q=1;q<5;q++) O[q]=off[rowbase+q-1]+rb;
#pragma unroll
      for(int i=0;i<4;i++){
        for(int j=O[i]; j<O[i+1]; j++){
          float4 p=pd[j];
          float wx = dr? p.x : 1.f-p.x;
          float uy=1.f-p.y, vy=p.y;
          float a0=wx*uy, a1=wx*vy;
          float wpu=p.x*uy, wpv=p.x*vy;
          w00[i]=fmaf(a0,a0,w00[i]);
          wE [i]=fmaf(a0,a1,wE [i]);
          gx [i]=fmaf(a0,p.z,gx[i]); gy[i]=fmaf(a0,p.w,gy[i]);
          if(!dr){ wS[i]=fmaf(a0,wpu,wS[i]); wSE[i]=fmaf(a0,wpv,wSE[i]); }
          if (i<=2){
            w00[i+1]=fmaf(a1,a1,w00[i+1]);
            gx [i+1]=fmaf(a1,p.z,gx[i+1]); gy[i+1]=fmaf(a1,p.w,gy[i+1]);
            if(!dr){ wS[i+1]=fmaf(a1,wpv,wS[i+1]); wSW[i+1]=fmaf(a1,wpu,wSW[i+1]); }
          }
        }
      }
    }
  }
  size_t base=((size_t)r<<10)+c0;
  store_h4(&WpH[base],               w00);
  store_h4(&WpH[(size_t)HW_+base],   wE );
  store_h4(&WpH[(size_t)2*HW_+base], wS );
  store_h4(&WpH[(size_t)3*HW_+base], wSE);
  store_h4(&WpH[(size_t)4*HW_+base], wSW);
#pragma unroll
  for(int q=0;q<4;q++) GyH[base+q]=__floats2half2_rn(gx[q],gy[q]);
}

// ---------------------------------------------------------------- 9-tap symmetric stencil, complex field (fp16 weights)
__device__ __forceinline__ float2 t_tap(const float2* __restrict__ Fm, const float2* __restrict__ F0,
                                        const float2* __restrict__ Fp, const __half* __restrict__ WpH,
                                        int rowW, int rowWm, int c){
  int cm=(c+1023)&1023, cp=(c+1)&1023;
  const __half* W00=WpH;
  const __half* WE =WpH+(size_t)HW_;
  const __half* WS =WpH+(size_t)2*HW_;
  const __half* WSE=WpH+(size_t)3*HW_;
  const __half* WSW=WpH+(size_t)4*HW_;
  float2 f=F0[c];
  float w=__half2float(W00[rowW+c]);
  float ux=w*f.x, uy=w*f.y;
  f=F0[cp]; w=__half2float(WE [rowW +c ]); ux=fmaf(w,f.x,ux); uy=fmaf(w,f.y,uy);  // +E
  f=F0[cm]; w=__half2float(WE [rowW +cm]); ux=fmaf(w,f.x,ux); uy=fmaf(w,f.y,uy);  // -E
  f=Fp[c ]; w=__half2float(WS [rowW +c ]); ux=fmaf(w,f.x,ux); uy=fmaf(w,f.y,uy);  // +S
  f=Fm[c ]; w=__half2float(WS [rowWm+c ]); ux=fmaf(w,f.x,ux); uy=fmaf(w,f.y,uy);  // -S
  f=Fp[cp]; w=__half2float(WSE[rowW +c ]); ux=fmaf(w,f.x,ux); uy=fmaf(w,f.y,uy);  // +SE
  f=Fm[cm]; w=__half2float(WSE[rowWm+cm]); ux=fmaf(w,f.x,ux); uy=fmaf(w,f.y,uy);  // -SE
  f=Fp[cm]; w=__half2float(WSW[rowW +c ]); ux=fmaf(w,f.x,ux); uy=fmaf(w,f.y,uy);  // +SW
  f=Fm[cp]; w=__half2float(WSW[rowWm+cp]); ux=fmaf(w,f.x,ux); uy=fmaf(w,f.y,uy);  // -SW
  return make_float2(ux,uy);
}

// ---------------------------------------------------------------- single-block power iteration on the 21x21 support
// S_1 = 1024*T(:,DC) has 9 nonzeros; T couples +-1 cell/application, so after
// 10 applications the support is <= +-10. The full power chain (init + 9
// normalized sweeps + op-norm finalization) runs in one block on a 25x25
// wrapped patch. Arithmetic per nonzero cell is identical to the full-grid
// version (same fmaf tap order, same fp16 weights, same eps chain).
__global__ __launch_bounds__(256) void k_power(const __half* __restrict__ WpH,
                                               const float* __restrict__ wraw,
                                               float* __restrict__ t){
  __shared__ float Wp5[5][25][25];   // wrapped weight window, offsets -12..+12
  __shared__ float Fa[25][25], Fb[25][25];
  __shared__ float red[8];
  int tid=threadIdx.x;
  // stage weights (grid coord = (patch+1012)&1023)
  for(int idx=tid; idx<3125; idx+=256){
    int d=idx/625, rem=idx-d*625, pr=rem/25, pc=rem-(rem/25)*25;
    int gr=(pr+1012)&1023, gc=(pc+1012)&1023;
    Wp5[d][pr][pc]=__half2float(WpH[(size_t)d*HW_+((size_t)gr<<10)+gc]);
  }
  for(int idx=tid; idx<625; idx+=256){
    int pr=idx/25, pc=idx-(idx/25)*25;
    Fa[pr][pc]=0.f; Fb[pr][pc]=0.f;
  }
  __syncthreads();
  // init: S_1 = 1024*T(:,DC)  (9 entries around center 12,12)
  if (tid==0){
    float bb=0.f, v;
    v=1024.f*Wp5[0][12][12]; Fa[12][12]=v; bb=fmaf(v,v,bb);   // ( 0, 0)
    v=1024.f*Wp5[1][12][12]; Fa[12][13]=v; bb=fmaf(v,v,bb);   // ( 0, 1)
    v=1024.f*Wp5[1][12][11]; Fa[12][11]=v; bb=fmaf(v,v,bb);   // ( 0,-1)
    v=1024.f*Wp5[2][12][12]; Fa[13][12]=v; bb=fmaf(v,v,bb);   // ( 1, 0)
    v=1024.f*Wp5[3][12][12]; Fa[13][13]=v; bb=fmaf(v,v,bb);   // ( 1, 1)
    v=1024.f*Wp5[4][12][12]; Fa[13][11]=v; bb=fmaf(v,v,bb);   // ( 1,-1)
    v=1024.f*Wp5[2][11][12]; Fa[11][12]=v; bb=fmaf(v,v,bb);   // (-1, 0)
    v=1024.f*Wp5[4][11][13]; Fa[11][13]=v; bb=fmaf(v,v,bb);   // (-1, 1)
    v=1024.f*Wp5[3][11][11]; Fa[11][11]=v; bb=fmaf(v,v,bb);   // (-1,-1)
    red[0]=bb;
  }
  __syncthreads();
  float b=red[0];
  float (*cur)[25]=Fa, (*nxt)[25]=Fb;
  int lane=tid&63, wid=tid>>6;
  for(int n=0;n<9;n++){
    float sc=1.f/(sqrtf(b)+1e-12f);
    float dot=0.f, nsq=0.f;
    for(int idx=tid; idx<441; idx+=256){
      int pr=2+idx/21, pc=2+(idx-(idx/21)*21);
      float u = Wp5[0][pr][pc]*cur[pr][pc];
      u=fmaf(Wp5[1][pr][pc  ],cur[pr  ][pc+1],u);
      u=fmaf(Wp5[1][pr][pc-1],cur[pr  ][pc-1],u);
      u=fmaf(Wp5[2][pr][pc  ],cur[pr+1][pc  ],u);
      u=fmaf(Wp5[2][pr-1][pc],cur[pr-1][pc  ],u);
      u=fmaf(Wp5[3][pr][pc  ],cur[pr+1][pc+1],u);
      u=fmaf(Wp5[3][pr-1][pc-1],cur[pr-1][pc-1],u);
      u=fmaf(Wp5[4][pr][pc  ],cur[pr+1][pc-1],u);
      u=fmaf(Wp5[4][pr-1][pc+1],cur[pr-1][pc+1],u);
      dot=fmaf(cur[pr][pc],u,dot);
      float o=u*sc;
      nsq=fmaf(o,o,nsq);
      nxt[pr][pc]=o;
    }
    for(int o=32;o>0;o>>=1){ dot+=__shfl_down(dot,o,64); nsq+=__shfl_down(nsq,o,64); }
    __syncthreads();                 // tap reads + prior red reads complete
    if(lane==0){ red[wid]=nsq; red[4+wid]=dot; }
    __syncthreads();
    if(tid==0){
      float nsum=red[0]+red[1]+red[2]+red[3];
      float dsum=red[4]+red[5]+red[6]+red[7];
      if (n==8){
        float a=sc*sc*dsum;          // ||av_10||^2
        float vn=sqrtf(b)*sc;        // ||v_9||
        float opn=sqrtf(a)/(vn+1e-12f);
        float sig=1.f/(1.f+__expf(-wraw[0]));
        t[19]=2.f*sig/(opn*opn);
      }
      red[0]=nsum;
    }
    __syncthreads();
    b=red[0];
    float (*tmp)[25]=cur; cur=nxt; nxt=tmp;
  }
}

// ---------------------------------------------------------------- npcg: G2_row = rowIFFT( T*F - Gy ), block = k-grid row (fp16 I/O, padded)
__global__ __launch_bounds__(256) void k_Tsub_fft(const __half2* __restrict__ Fin,
    const __half* __restrict__ WpH, const __half2* __restrict__ GyH,
    __half2* __restrict__ G2, float scale){
  __shared__ __align__(16) float2 Fsm[3][1024];   // reused as FFT scratch A|B after taps
  int r=blockIdx.x, tid=threadIdx.x;
  int rm=(r+1023)&1023, rp=(r+1)&1023;
  {
    const __half2* s0=Fin+(size_t)rm*LDW_;
    const __half2* s1=Fin+(size_t)r *LDW_;
    const __half2* s2=Fin+(size_t)rp*LDW_;
    for(int p2=tid;p2<1024;p2+=256){
      Fsm[0][p2]=__half22float2(s0[p2]);
      Fsm[1][p2]=__half22float2(s1[p2]);
      Fsm[2][p2]=__half22float2(s2[p2]);
    }
  }
  __syncthreads();
  int rowW=r<<10, rowWm=rm<<10;
  float2 v[4];
  const __half2* gyr=GyH+((size_t)r<<10);
#pragma unroll
  for(int q=0;q<4;q++){
    int c=tid+256*q;
    float2 u=t_tap(&Fsm[0][0],&Fsm[1][0],&Fsm[2][0],WpH,rowW,rowWm,c);
    float2 gy=__half22float2(gyr[c]);
    v[q]=make_float2(u.x-gy.x,u.y-gy.y);   // note: c = tid+256q IS the fft1024_core input layout
  }
  __syncthreads();                          // all Fsm reads done before aliasing
  float2* A=(float2*)Fsm; float2* B=A+1088;
  fft1024_core<1>(v,tid,A,B,scale);
  __half2* d=G2+(size_t)r*LDW_;
#pragma unroll
  for(int rr=0;rr<4;rr++) d[tid+256*rr]=__floats2half2_rn(v[rr].x,v[rr].y);
}

// ---------------------------------------------------------------- fused 5x5 composed CNN + update (res in fp16, padded LDW_)
// blocks 0..1023: interior tiles (skip border pixels); blocks 1024..1039: border ring
#define CT_S 41
__global__ __launch_bounds__(256) void k_cnn5(const float2* __restrict__ x, const __half2* __restrict__ res,
    const float* __restrict__ ec, const float* __restrict__ t,
    float2* __restrict__ xout, float* __restrict__ outPlanar){
  int tid=threadIdx.x;
  if (blockIdx.x>=1024){
    // ---- border ring: exact conv2(conv1) with h zero-masked outside image
    int id = (blockIdx.x-1024)*256+tid;   // 4096
    int py,px;
    if (id<1024){ py=0; px=id; }
    else if(id<2048){ py=1023; px=id-1024; }
    else if(id<3072){ py=id-2048; px=0; }
    else { py=id-3072; px=1023; }
    float s0=ec[444], s1=ec[445];
    for(int uy=0;uy<3;uy++){
      int qy=py+uy-1; if((unsigned)qy>=1024u) continue;
      for(int ux=0;ux<3;ux++){
        int qx=px+ux-1; if((unsigned)qx>=1024u) continue;
        int u=uy*3+ux;
        s0+=ec[102+u]; s1+=ec[111+u];
        const float* B0=&ec[120+u*18];
        const float* B1=&ec[282+u*18];
        for(int vy=0;vy<3;vy++){
          int sy2=qy+vy-1; if((unsigned)sy2>=1024u) continue;
          for(int vx=0;vx<3;vx++){
            int sx2=qx+vx-1; if((unsigned)sx2>=1024u) continue;
            int v=vy*3+vx;
            float2 xv=x[(size_t)sy2*W_+sx2];
            s0 = fmaf(B0[v],xv.x,fmaf(B0[9+v],xv.y,s0));
            s1 = fmaf(B1[v],xv.x,fmaf(B1[9+v],xv.y,s1));
          }
        }
      }
    }
    float wreg=t[19];
    size_t base=(size_t)py*W_+px;
    float2 xv=x[base];
    float2 rv=__half22float2(res[(size_t)py*LDW_+px]);
    float o0=xv.x - wreg*rv.x - s0;
    float o1=xv.y - wreg*rv.y - s1;
    if (outPlanar){ outPlanar[base]=o0; outPlanar[HW_+base]=o1; }
    else          { xout[base]=make_float2(o0,o1); }
    return;
  }
  __shared__ float xt0[36*CT_S];
  __shared__ float xt1[36*CT_S];
  __shared__ float sE[102];
  int by=blockIdx.x>>5, bx=blockIdx.x&31;
  int ty0=by<<5, tx0=bx<<5;
  for(int p=tid;p<102;p+=256) sE[p]=ec[p];
  for(int p=tid;p<1296;p+=256){
    int r=p/36, c=p-r*36;
    int gy=ty0-2+r, gx=tx0-2+c;
    float vx=0.f, vy=0.f;
    if((unsigned)gy<1024u && (unsigned)gx<1024u){ float2 v=x[(size_t)gy*W_+gx]; vx=v.x; vy=v.y; }
    xt0[r*CT_S+c]=vx; xt1[r*CT_S+c]=vy;
  }
  __syncthreads();
  int row=tid>>3, c4=(tid&7)<<2;
  float a0[4], a1[4];
  float C00=sE[100], C01=sE[101];
#pragma unroll
  for(int jj=0;jj<4;jj++){ a0[jj]=C00; a1[jj]=C01; }
#pragma unroll
  for(int dy=0;dy<5;dy++){
    const float* r0=&xt0[(row+dy)*CT_S+c4];
    const float* r1=&xt1[(row+dy)*CT_S+c4];
    float f0[9], f1[9];
#pragma unroll
    for(int q=0;q<9;q++){ f0[q]=r0[q]; f1[q]=r1[q]; }
#pragma unroll
    for(int dx=0;dx<5;dx++){
      float e00=sE[dy*5+dx], e01=sE[25+dy*5+dx];
      float e10=sE[50+dy*5+dx], e11=sE[75+dy*5+dx];
#pragma unroll
      for(int jj=0;jj<4;jj++){
        a0[jj]=fmaf(e00,f0[jj+dx],fmaf(e01,f1[jj+dx],a0[jj]));
        a1[jj]=fmaf(e10,f0[jj+dx],fmaf(e11,f1[jj+dx],a1[jj]));
      }
    }
  }
  int py=ty0+row;
  float wreg = t[19];
  size_t base=(size_t)py*W_ + tx0 + c4;
  size_t baseR=(size_t)py*LDW_ + tx0 + c4;
  bool rowEdge = (py==0)||(py==1023);
  if (outPlanar){
#pragma unroll
    for(int jj=0;jj<4;jj++){
      int px=tx0+c4+jj;
      if (rowEdge || px==0 || px==1023) continue;   // ring blocks own these
      float2 rv=__half22float2(res[baseR+jj]);
      float xr_=xt0[(row+2)*CT_S+c4+jj+2];
      float xi_=xt1[(row+2)*CT_S+c4+jj+2];
      outPlanar[base+jj]      = xr_ - wreg*rv.x - a0[jj];
      outPlanar[HW_+base+jj]  = xi_ - wreg*rv.y - a1[jj];
    }
  } else {
#pragma unroll
    for(int jj=0;jj<4;jj++){
      int px=tx0+c4+jj;
      if (rowEdge || px==0 || px==1023) continue;
      float2 rv=__half22float2(res[baseR+jj]);
      float xr_=xt0[(row+2)*CT_S+c4+jj+2];
      float xi_=xt1[(row+2)*CT_S+c4+jj+2];
      xout[base+jj]=make_float2(xr_ - wreg*rv.x - a0[jj],
                                xi_ - wreg*rv.y - a1[jj]);
    }
  }
}

// ================================================================ launch
extern "C" void kernel_launch(void* const* d_in, const int* in_sizes, int n_in,
                              void* d_out, int out_size, void* d_ws, size_t ws_size,
                              hipStream_t stream){
  (void)in_sizes; (void)n_in; (void)out_size; (void)ws_size;
  const float* xr  =(const float*)d_in[0];
  const float* xi  =(const float*)d_in[1];
  const float* kre =(const float*)d_in[2];
  const float* kim =(const float*)d_in[3];
  const float* kt  =(const float*)d_in[4];
  const float* wraw=(const float*)d_in[5];
  const float* w1  =(const float*)d_in[6];
  const float* b1  =(const float*)d_in[7];
  const float* w2  =(const float*)d_in[8];
  const float* b2  =(const float*)d_in[9];
  float* out = (float*)d_out;

  char* ws=(char*)d_ws;
  float2* Wx0 =(float2*)(ws);                      // 8MB
  float2* Wx1 =(float2*)(ws + ((size_t) 8<<20));   // 8MB
  int*   counts=(int*)  (ws + ((size_t) 8<<20));   // 4MB alias of Wx1 (setup only)
  __half2* WF =(__half2*)(ws + ((size_t)16<<20));  // ~4.1MB fwd-FFT k-grid (fp16, LDW_=1040)
  float4* pd  =(float4*)(ws + ((size_t)24<<20));   // 8MB  (tx,ty,ydcf.x,ydcf.y) sorted
  __half2* G2 =(__half2*)(ws + ((size_t)32<<20));  // ~4.1MB npcg residual grid (fp16, LDW_)
  int*  off   =(int*)   (ws + ((size_t)40<<20));   // 4MB  CSR ends (row-local)
  __half2* GyH=(__half2*)(ws + ((size_t)44<<20));  // 4MB  Grid(y*sqrt_dcf) fp16
  __half* WpH =(__half*)(ws + ((size_t)52<<20));   // 10MB 5 stencil planes (fp16)
  int*  bsum  =(int*)   (ws + ((size_t)62<<20));            // 4KB
  float* t    =(float*) (ws + ((size_t)62<<20) + 8192);
  float* ec   =(float*) (ws + ((size_t)62<<20) + 16384);
  float* pmax =(float*) (ws + ((size_t)62<<20) + 57344);    // 8KB
  const float SC = 0.03125f;   // 1/32 per 1-D ortho pass

  // ---- setup
  k_pack<<<HW_/256+1,256,0,stream>>>(xr,xi,Wx0,t,counts,w1,b1,w2,b2,ec);
  k_hist<<<M_/256,256,0,stream>>>(kt,counts,pmax);
  k_scan1<<<1025,256,0,stream>>>(counts,off,bsum,pmax,t);   // +block 1024: pmax -> t[15]
  k_scan2<<<1,256,0,stream>>>(bsum);
  k_reorder12<<<M_/256,256,0,stream>>>(kt,kre,kim,off,bsum,pd,t);
  k_mkWG<<<HW_/1024,256,0,stream>>>(pd,off,bsum,WpH,GyH);

  // ---- full power iteration + op-norm finalization in ONE single-block kernel
  k_power<<<1,256,0,stream>>>(WpH,wraw,t);

  // ---- npcg = 4 PGD iterations (k-space intermediates in fp16, padded LDW_)
  for (int it=0; it<4; it++){
    float2* xin  = (it&1)? Wx1 : Wx0;
    float2* xout = (it&1)? Wx0 : Wx1;
    float* planar = (it==3)? out : (float*)nullptr;
    k_fft_rows_f2h<-1><<<H_,256,0,stream>>>(xin,WF,SC);
    k_fft_cols1_h<-1><<<H_,256,0,stream>>>(WF,SC);
    k_Tsub_fft<<<H_,256,0,stream>>>(WF,WpH,GyH,G2,SC);
    k_fft_cols1_h<1><<<H_,256,0,stream>>>(G2,SC);
    k_cnn5<<<1040,256,0,stream>>>(xin,G2,ec,t,xout,planar);
  }
}